// Round 1
// baseline (1479.263 us; speedup 1.0000x reference)
//
#include <hip/hip_runtime.h>
#include <hip/hip_bf16.h>
#include <math.h>

// Problem constants (Segmenter_65721589563708)
constexpr int MT  = 8192;   // bs*n
constexpr int DF  = 768;    // feature dim
constexpr int KD  = 64;     // kdim
constexpr int HWP = 1024;   // 32*32 pixels
constexpr int KF  = 32;     // feature kNN
constexpr int KP  = 10;     // pixel kNN
constexpr int RB  = 1024;   // GEMM row-block
#define SQT 3.16227766016837933f   // sqrt(T=10)
#define PIXW 0.05f

typedef __bf16 bf16x8 __attribute__((ext_vector_type(8)));
typedef float  f32x4  __attribute__((ext_vector_type(4)));

// ---------------- 1. normalize rows of X, split into bf16 hi + lo ----------------
__global__ __launch_bounds__(256) void norm_split_kernel(const float* __restrict__ X,
                                                         __bf16* __restrict__ Xhi,
                                                         __bf16* __restrict__ Xlo) {
  __shared__ float red[256];
  const int row = blockIdx.x, tid = threadIdx.x;
  const float* xr = X + (size_t)row * DF;
  float s = 0.f;
  for (int c = tid; c < DF; c += 256) { float v = xr[c]; s += v * v; }
  red[tid] = s; __syncthreads();
  for (int o = 128; o > 0; o >>= 1) { if (tid < o) red[tid] += red[tid + o]; __syncthreads(); }
  const float rn = rsqrtf(red[0]);
  __bf16* hr = Xhi + (size_t)row * DF;
  __bf16* lr = Xlo + (size_t)row * DF;
  for (int c = tid; c < DF; c += 256) {
    float v = xr[c] * rn;
    __bf16 h = (__bf16)v;
    hr[c] = h;
    lr[c] = (__bf16)(v - (float)h);
  }
}

// ---------------- 2. S row-block = Xcat[rb] . Xcat^T  (virtual K = 3*768) ----------------
// Hi.Hi^T + Hi.Lo^T + Lo.Hi^T  ~= fp32-accurate cosine similarity
__global__ __launch_bounds__(256) void gemm_kernel(const __bf16* __restrict__ Xhi,
                                                   const __bf16* __restrict__ Xlo,
                                                   float* __restrict__ Sblk, int rowBase) {
  __shared__ __bf16 As[128 * 64];
  __shared__ __bf16 Bs[128 * 64];
  const int tid = threadIdx.x;
  const int lane = tid & 63;
  const int w = tid >> 6;
  const int wm = (w & 1) * 64, wn = (w >> 1) * 64;
  const int n0 = blockIdx.x * 128;
  const int m0 = blockIdx.y * 128;
  const int l15 = lane & 15, lq = lane >> 4;

  f32x4 acc[4][4];
  #pragma unroll
  for (int i = 0; i < 4; ++i)
    #pragma unroll
    for (int j = 0; j < 4; ++j)
      #pragma unroll
      for (int r = 0; r < 4; ++r) acc[i][j][r] = 0.f;

  for (int kt = 0; kt < 36; ++kt) {
    const int region = kt / 12;
    const int col0 = (kt % 12) * 64;
    const __bf16* Asrc = (kt < 24) ? Xhi : Xlo;
    const __bf16* Bsrc = (region == 1) ? Xlo : Xhi;
    #pragma unroll
    for (int i = 0; i < 4; ++i) {   // stage 128x64 bf16 A and B tiles
      int c = tid + i * 256;
      int r = c >> 3, c8 = c & 7;
      uint4 va = *(const uint4*)(Asrc + (size_t)(rowBase + m0 + r) * DF + col0 + c8 * 8);
      uint4 vb = *(const uint4*)(Bsrc + (size_t)(n0 + r) * DF + col0 + c8 * 8);
      *(uint4*)(&As[r * 64 + c8 * 8]) = va;
      *(uint4*)(&Bs[r * 64 + c8 * 8]) = vb;
    }
    __syncthreads();
    #pragma unroll
    for (int kk = 0; kk < 64; kk += 32) {
      bf16x8 af[4], bg[4];
      #pragma unroll
      for (int i = 0; i < 4; ++i)
        af[i] = *(const bf16x8*)(&As[(wm + i * 16 + l15) * 64 + kk + lq * 8]);
      #pragma unroll
      for (int j = 0; j < 4; ++j)
        bg[j] = *(const bf16x8*)(&Bs[(wn + j * 16 + l15) * 64 + kk + lq * 8]);
      #pragma unroll
      for (int i = 0; i < 4; ++i)
        #pragma unroll
        for (int j = 0; j < 4; ++j)
          acc[i][j] = __builtin_amdgcn_mfma_f32_16x16x32_bf16(af[i], bg[j], acc[i][j], 0, 0, 0);
    }
    __syncthreads();
  }
  // C/D layout: col = lane&15, row = (lane>>4)*4 + reg   [m89/m91 verified]
  #pragma unroll
  for (int i = 0; i < 4; ++i)
    #pragma unroll
    for (int j = 0; j < 4; ++j)
      #pragma unroll
      for (int r = 0; r < 4; ++r) {
        int lrow = m0 + wm + i * 16 + lq * 4 + r;
        int col  = n0 + wn + j * 16 + l15;
        Sblk[(size_t)lrow * MT + col] = acc[i][j][r];
      }
}

// ---------------- 3. top-32 per row (clamped at 0, diag excluded) ----------------
__global__ __launch_bounds__(256) void topk_kernel(const float* __restrict__ Sblk,
                                                   int* __restrict__ fidx,
                                                   float* __restrict__ fval, int rowBase) {
  __shared__ float sv[MT];
  __shared__ float rv[4];
  __shared__ int   ri[4];
  const int tid = threadIdx.x;
  const int rl = blockIdx.x;
  const int grow = rowBase + rl;
  const float* srow = Sblk + (size_t)rl * MT;
  for (int c = tid; c < MT; c += 256) {
    float v = srow[c];
    sv[c] = (c == grow) ? -1.f : fmaxf(v, 0.f);
  }
  __syncthreads();
  for (int it = 0; it < KF; ++it) {
    float bm = -2.f; int bi = 0;
    for (int c = tid; c < MT; c += 256) {
      float v = sv[c];
      if (v > bm) { bm = v; bi = c; }
    }
    #pragma unroll
    for (int o = 32; o > 0; o >>= 1) {
      float ov = __shfl_down(bm, o);
      int   oi = __shfl_down(bi, o);
      if (ov > bm) { bm = ov; bi = oi; }
    }
    if ((tid & 63) == 0) { rv[tid >> 6] = bm; ri[tid >> 6] = bi; }
    __syncthreads();
    if (tid == 0) {
      float m = rv[0]; int mi = ri[0];
      #pragma unroll
      for (int q = 1; q < 4; ++q) if (rv[q] > m) { m = rv[q]; mi = ri[q]; }
      fval[(size_t)grow * KF + it] = (m > 0.f) ? m : 0.f;  // zero-valued picks contribute nothing
      fidx[(size_t)grow * KF + it] = mi;
      sv[mi] = -1.f;
    }
    __syncthreads();
  }
}

// ---------------- 4. pixel kNN: two distance weightings, union r|r^T into bitmask ----------------
__global__ __launch_bounds__(128) void pix_topk_kernel(const float* __restrict__ im,
                                                       unsigned* __restrict__ pmask) {
  __shared__ float fr[HWP], fg[HWP], fb[HWP];
  __shared__ float dd[2][HWP];
  __shared__ float rv[2];
  __shared__ int   ri[2];
  const int tid = threadIdx.x;
  const int b = blockIdx.x >> 10;
  const int p = blockIdx.x & 1023;
  const float* imb = im + (size_t)b * 3 * HWP;
  for (int q = tid; q < HWP; q += 128) {
    fr[q] = (imb[q] + 1.f) * 0.5f;
    fg[q] = (imb[HWP + q] + 1.f) * 0.5f;
    fb[q] = (imb[2 * HWP + q] + 1.f) * 0.5f;
  }
  __syncthreads();
  const float pr = fr[p], pg = fg[p], pb = fb[p];
  const float px = (float)(p & 31) * (1.f / 31.f), py = (float)(p >> 5) * (1.f / 31.f);
  for (int q = tid; q < HWP; q += 128) {
    float dr = fr[q] - pr, dg = fg[q] - pg, db = fb[q] - pb;
    float drgb = dr * dr + dg * dg + db * db;
    float dx = (float)(q & 31) * (1.f / 31.f) - px;
    float dy = (float)(q >> 5) * (1.f / 31.f) - py;
    float cd = dx * dx + dy * dy;
    dd[0][q] = (q == p) ? 1e30f : (drgb + 4.00f * cd);  // dw = 2.0
    dd[1][q] = (q == p) ? 1e30f : (drgb + 0.01f * cd);  // dw = 0.1
  }
  __syncthreads();
  const int mrow = blockIdx.x;   // b*1024 + p
  for (int pass = 0; pass < 2; ++pass) {
    for (int it = 0; it < KP; ++it) {
      float bm = 1e30f; int bi = 0;
      for (int q = tid; q < HWP; q += 128) {
        float v = dd[pass][q];
        if (v < bm) { bm = v; bi = q; }
      }
      #pragma unroll
      for (int o = 32; o > 0; o >>= 1) {
        float ov = __shfl_down(bm, o);
        int   oi = __shfl_down(bi, o);
        if (ov < bm) { bm = ov; bi = oi; }
      }
      if ((tid & 63) == 0) { rv[tid >> 6] = bm; ri[tid >> 6] = bi; }
      __syncthreads();
      if (tid == 0) {
        int q = (rv[1] < rv[0]) ? ri[1] : ri[0];
        atomicOr(&pmask[(size_t)mrow * 32 + (q >> 5)], 1u << (q & 31));
        atomicOr(&pmask[((size_t)(b * HWP + q)) * 32 + (p >> 5)], 1u << (p & 31));
        dd[pass][q] = 1e30f;
      }
      __syncthreads();
    }
  }
}

// ---------------- 5. degrees -> rsqrt ----------------
__global__ void pix_deg_kernel(const unsigned* __restrict__ pmask, float* __restrict__ d2r) {
  int m = blockIdx.x * blockDim.x + threadIdx.x;
  if (m >= MT) return;
  int deg = 0;
  for (int w = 0; w < 32; ++w) deg += __popc(pmask[(size_t)m * 32 + w]);
  d2r[m] = (deg > 0) ? rsqrtf((float)deg) : 0.f;
}

__global__ void feat_deg_kernel(const int* __restrict__ fidx, const float* __restrict__ fval,
                                float* __restrict__ frow) {
  int m = blockIdx.x * blockDim.x + threadIdx.x;
  if (m >= MT) return;
  float s = 0.f;
  for (int k = 0; k < KF; ++k) {
    float v = fval[m * KF + k];
    s += v;
    atomicAdd(&frow[fidx[m * KF + k]], 0.5f * v);
  }
  atomicAdd(&frow[m], 0.5f * s);
}

__global__ void feat_rsqrt_kernel(const float* __restrict__ frow, float* __restrict__ dfeat) {
  int m = blockIdx.x * blockDim.x + threadIdx.x;
  if (m >= MT) return;
  float s = frow[m];
  dfeat[m] = (s > 0.f) ? rsqrtf(s) : 0.f;
}

// ---------------- 6. gP = gram_feat @ Psi'  (sparse scatter/gather, atomics) ----------------
__global__ __launch_bounds__(64) void gp_feat_kernel(const int* __restrict__ fidx,
                                                     const float* __restrict__ fval,
                                                     const float* __restrict__ dfeat,
                                                     const float* __restrict__ Psi,
                                                     float* __restrict__ gP) {
  const int j = blockIdx.x;
  const int t = threadIdx.x;
  const float pj = Psi[(size_t)j * KD + t] * SQT;
  const float dj = dfeat[j];
  float accj = 0.f;
  for (int k = 0; k < KF; ++k) {
    float v = fval[j * KF + k];
    int   c = fidx[j * KF + k];
    float wgt = 0.5f * v * dj * dfeat[c];
    accj += wgt * Psi[(size_t)c * KD + t] * SQT;
    atomicAdd(&gP[(size_t)c * KD + t], wgt * pj);
  }
  atomicAdd(&gP[(size_t)j * KD + t], accj);
}

// ---------------- 7. gP += PIXW * gram_pix @ Psi' ----------------
__global__ __launch_bounds__(64) void gp_pix_kernel(const unsigned* __restrict__ pmask,
                                                    const float* __restrict__ d2r,
                                                    const float* __restrict__ Psi,
                                                    float* __restrict__ gP) {
  __shared__ int list[HWP];
  __shared__ int cnt;
  const int m = blockIdx.x;
  const int t = threadIdx.x;
  const int b = m >> 10;
  if (t == 0) cnt = 0;
  __syncthreads();
  if (t < 32) {
    unsigned bits = pmask[(size_t)m * 32 + t];
    while (bits) {
      int bit = __ffs(bits) - 1;
      bits &= bits - 1;
      int pos = atomicAdd(&cnt, 1);
      list[pos] = t * 32 + bit;
    }
  }
  __syncthreads();
  const int n = cnt;
  float acc = 0.f;
  for (int e = 0; e < n; ++e) {
    int g = b * HWP + list[e];
    acc += d2r[g] * Psi[(size_t)g * KD + t];
  }
  gP[(size_t)m * KD + t] += PIXW * d2r[m] * acc * SQT;
}

// ---------------- 8. R = Psi'^T @ gP ----------------
__global__ __launch_bounds__(64) void r_kernel(const float* __restrict__ Psi,
                                               const float* __restrict__ gP,
                                               float* __restrict__ Rm) {
  const int a = blockIdx.x;
  const int t = threadIdx.x;
  const int mBeg = blockIdx.y * 512;
  float acc = 0.f;
  #pragma unroll 4
  for (int m = mBeg; m < mBeg + 512; ++m)
    acc += Psi[(size_t)m * KD + a] * gP[(size_t)m * KD + t];
  atomicAdd(&Rm[a * KD + t], acc * SQT);
}

// ---------------- 9. loss = -tr(R)/kd ; reg = sum(triu(R^2,1))/kd ----------------
__global__ __launch_bounds__(256) void final_kernel(const float* __restrict__ Rm,
                                                    float* __restrict__ out) {
  __shared__ float redt[256], redr[256];
  const int tid = threadIdx.x;
  float tr = 0.f, rg = 0.f;
  for (int e = tid; e < KD * KD; e += 256) {
    int a = e >> 6, c = e & 63;
    float v = Rm[e];
    if (a == c) tr += v;
    else if (c > a) rg += v * v;
  }
  redt[tid] = tr; redr[tid] = rg;
  __syncthreads();
  for (int o = 128; o > 0; o >>= 1) {
    if (tid < o) { redt[tid] += redt[tid + o]; redr[tid] += redr[tid + o]; }
    __syncthreads();
  }
  if (tid == 0) {
    out[0] = -redt[0] / (float)KD;
    out[1] = redr[0] / (float)KD;
  }
}

extern "C" void kernel_launch(void* const* d_in, const int* in_sizes, int n_in,
                              void* d_out, int out_size, void* d_ws, size_t ws_size,
                              hipStream_t stream) {
  const float* hl  = (const float*)d_in[0];   // [8,1024,768]
  const float* Psi = (const float*)d_in[1];   // [8,1024,64]
  const float* im  = (const float*)d_in[2];   // [8,3,32,32]
  float* out = (float*)d_out;

  char* ws = (char*)d_ws;
  size_t off = 0;
  auto alloc = [&](size_t bytes) -> void* {
    void* p = ws + off;
    off = (off + bytes + 255) & ~(size_t)255;
    return p;
  };
  __bf16*  Xhi   = (__bf16*)alloc((size_t)MT * DF * 2);
  __bf16*  Xlo   = (__bf16*)alloc((size_t)MT * DF * 2);
  float*   Sblk  = (float*)alloc((size_t)RB * MT * 4);
  int*     fidx  = (int*)alloc((size_t)MT * KF * 4);
  float*   fval  = (float*)alloc((size_t)MT * KF * 4);
  float*   frow  = (float*)alloc((size_t)MT * 4);
  float*   dfeat = (float*)alloc((size_t)MT * 4);
  unsigned* pmask = (unsigned*)alloc((size_t)MT * 32 * 4);
  float*   d2r   = (float*)alloc((size_t)MT * 4);
  float*   gP    = (float*)alloc((size_t)MT * KD * 4);
  float*   Rm    = (float*)alloc((size_t)KD * KD * 4);

  hipMemsetAsync(frow,  0, (size_t)MT * 4, stream);
  hipMemsetAsync(pmask, 0, (size_t)MT * 32 * 4, stream);
  hipMemsetAsync(gP,    0, (size_t)MT * KD * 4, stream);
  hipMemsetAsync(Rm,    0, (size_t)KD * KD * 4, stream);

  norm_split_kernel<<<MT, 256, 0, stream>>>(hl, Xhi, Xlo);
  pix_topk_kernel<<<MT, 128, 0, stream>>>(im, pmask);
  pix_deg_kernel<<<MT / 256, 256, 0, stream>>>(pmask, d2r);

  for (int rb = 0; rb < MT / RB; ++rb) {
    gemm_kernel<<<dim3(MT / 128, RB / 128), 256, 0, stream>>>(Xhi, Xlo, Sblk, rb * RB);
    topk_kernel<<<RB, 256, 0, stream>>>(Sblk, fidx, fval, rb * RB);
  }

  feat_deg_kernel<<<MT / 256, 256, 0, stream>>>(fidx, fval, frow);
  feat_rsqrt_kernel<<<MT / 256, 256, 0, stream>>>(frow, dfeat);
  gp_feat_kernel<<<MT, 64, 0, stream>>>(fidx, fval, dfeat, Psi, gP);
  gp_pix_kernel<<<MT, 64, 0, stream>>>(pmask, d2r, Psi, gP);
  r_kernel<<<dim3(KD, 16), 64, 0, stream>>>(Psi, gP, Rm);
  final_kernel<<<1, 256, 0, stream>>>(Rm, out);
}

// Round 2
// 1073.641 us; speedup vs baseline: 1.3778x; 1.3778x over previous
//
#include <hip/hip_runtime.h>
#include <hip/hip_bf16.h>
#include <math.h>

// Problem constants (Segmenter_65721589563708)
constexpr int MT  = 8192;   // bs*n
constexpr int DF  = 768;    // feature dim
constexpr int KD  = 64;     // kdim
constexpr int HWP = 1024;   // 32*32 pixels
constexpr int KF  = 32;     // feature kNN
constexpr int KP  = 10;     // pixel kNN
constexpr int RB  = 1024;   // GEMM row-block
#define SQT 3.16227766016837933f   // sqrt(T=10)
#define PIXW 0.05f

typedef __bf16 bf16x8 __attribute__((ext_vector_type(8)));
typedef float  f32x4  __attribute__((ext_vector_type(4)));

// ---------------- 1. normalize rows of X, split into bf16 hi + lo ----------------
__global__ __launch_bounds__(256) void norm_split_kernel(const float* __restrict__ X,
                                                         __bf16* __restrict__ Xhi,
                                                         __bf16* __restrict__ Xlo) {
  __shared__ float red[256];
  const int row = blockIdx.x, tid = threadIdx.x;
  const float* xr = X + (size_t)row * DF;
  float s = 0.f;
  for (int c = tid; c < DF; c += 256) { float v = xr[c]; s += v * v; }
  red[tid] = s; __syncthreads();
  for (int o = 128; o > 0; o >>= 1) { if (tid < o) red[tid] += red[tid + o]; __syncthreads(); }
  const float rn = rsqrtf(red[0]);
  __bf16* hr = Xhi + (size_t)row * DF;
  __bf16* lr = Xlo + (size_t)row * DF;
  for (int c = tid; c < DF; c += 256) {
    float v = xr[c] * rn;
    __bf16 h = (__bf16)v;
    hr[c] = h;
    lr[c] = (__bf16)(v - (float)h);
  }
}

// ---------------- 2. S row-block = Xcat[rb] . Xcat^T  (virtual K = 3*768) ----------------
// Hi.Hi^T + Hi.Lo^T + Lo.Hi^T ~= fp32-accurate cosine similarity.
// m97-style: global_load_lds width=16 staging (wave-uniform LDS base + lane*16B).
__global__ __launch_bounds__(256) void gemm_kernel(const __bf16* __restrict__ Xhi,
                                                   const __bf16* __restrict__ Xlo,
                                                   float* __restrict__ Sblk, int rowBase) {
  __shared__ __bf16 As[128 * 64];
  __shared__ __bf16 Bs[128 * 64];
  const int tid = threadIdx.x;
  const int lane = tid & 63;
  const int wv = tid >> 6;
  const int wm = (wv & 1) * 64, wn = (wv >> 1) * 64;
  const int n0 = blockIdx.x * 128;
  const int m0 = blockIdx.y * 128;
  const int l15 = lane & 15, lq = lane >> 4;
  const int lr8 = lane >> 3, lc8 = lane & 7;   // staging: row-in-group, 16B-chunk

  f32x4 acc[4][4];
  #pragma unroll
  for (int i = 0; i < 4; ++i)
    #pragma unroll
    for (int j = 0; j < 4; ++j)
      #pragma unroll
      for (int r = 0; r < 4; ++r) acc[i][j][r] = 0.f;

  for (int kt = 0; kt < 36; ++kt) {
    const int region = kt / 12;
    const int col0 = (kt % 12) * 64;
    const __bf16* Asrc = (kt < 24) ? Xhi : Xlo;
    const __bf16* Bsrc = (region == 1) ? Xlo : Xhi;
    const __bf16* Ag = Asrc + (size_t)(rowBase + m0) * DF + col0;
    const __bf16* Bg = Bsrc + (size_t)n0 * DF + col0;
    #pragma unroll
    for (int i = 0; i < 4; ++i) {
      const int r0 = (wv * 4 + i) * 8;         // 8 rows per issue, wave-uniform
      __builtin_amdgcn_global_load_lds(
          (const __attribute__((address_space(1))) void*)(Ag + (size_t)(r0 + lr8) * DF + lc8 * 8),
          (__attribute__((address_space(3))) void*)(&As[r0 * 64]), 16, 0, 0);
      __builtin_amdgcn_global_load_lds(
          (const __attribute__((address_space(1))) void*)(Bg + (size_t)(r0 + lr8) * DF + lc8 * 8),
          (__attribute__((address_space(3))) void*)(&Bs[r0 * 64]), 16, 0, 0);
    }
    __syncthreads();
    #pragma unroll
    for (int kk = 0; kk < 64; kk += 32) {
      bf16x8 af[4], bg[4];
      #pragma unroll
      for (int i = 0; i < 4; ++i)
        af[i] = *(const bf16x8*)(&As[(wm + i * 16 + l15) * 64 + kk + lq * 8]);
      #pragma unroll
      for (int j = 0; j < 4; ++j)
        bg[j] = *(const bf16x8*)(&Bs[(wn + j * 16 + l15) * 64 + kk + lq * 8]);
      #pragma unroll
      for (int i = 0; i < 4; ++i)
        #pragma unroll
        for (int j = 0; j < 4; ++j)
          acc[i][j] = __builtin_amdgcn_mfma_f32_16x16x32_bf16(af[i], bg[j], acc[i][j], 0, 0, 0);
    }
    __syncthreads();
  }
  // C/D layout: col = lane&15, row = (lane>>4)*4 + reg   [m89/m91 verified]
  #pragma unroll
  for (int i = 0; i < 4; ++i)
    #pragma unroll
    for (int j = 0; j < 4; ++j)
      #pragma unroll
      for (int r = 0; r < 4; ++r) {
        int lrow = m0 + wm + i * 16 + lq * 4 + r;
        int col  = n0 + wn + j * 16 + l15;
        Sblk[(size_t)lrow * MT + col] = acc[i][j][r];
      }
}

// ---------------- 3. top-32 per row via histogram threshold + candidate select ----------------
constexpr int NB   = 1024;   // histogram bins over [0,1]
constexpr int CAND = 2048;   // candidate cap (expected ~33 with random data)

__global__ __launch_bounds__(256) void topk_kernel(const float* __restrict__ Sblk,
                                                   int* __restrict__ fidx,
                                                   float* __restrict__ fval, int rowBase) {
  __shared__ int   hist[NB];
  __shared__ int   chunk[256];
  __shared__ float cval[CAND];
  __shared__ int   cidx[CAND];
  __shared__ int   cnt, tbin;
  const int tid = threadIdx.x;
  const int rl = blockIdx.x;
  const int grow = rowBase + rl;
  const float* srow = Sblk + (size_t)rl * MT;
  #pragma unroll
  for (int i = tid; i < NB; i += 256) hist[i] = 0;
  if (tid == 0) cnt = 0;
  __syncthreads();
  // pass 1: histogram of positive, non-diagonal values
  for (int c = tid; c < MT; c += 256) {
    float v = srow[c];
    if (c != grow && v > 0.f) {
      int b = (int)fminf(v * (float)NB, (float)(NB - 1));
      atomicAdd(&hist[b], 1);
    }
  }
  __syncthreads();
  { int s = 0;
    #pragma unroll
    for (int i = 0; i < 4; ++i) s += hist[tid * 4 + i];
    chunk[tid] = s; }
  __syncthreads();
  if (tid == 0) {
    int acc = 0, ch = 255;
    for (; ch > 0; --ch) {
      if (acc + chunk[ch] >= KF) break;
      acc += chunk[ch];
    }
    int b = ch * 4 + 3;
    for (; b > ch * 4; --b) {
      if (acc + hist[b] >= KF) break;
      acc += hist[b];
    }
    tbin = b;   // bins >= tbin hold >= KF values (or everything if row degenerate)
  }
  __syncthreads();
  const int T = tbin;
  // pass 2: collect candidates in bins >= T
  for (int c = tid; c < MT; c += 256) {
    float v = srow[c];
    if (c != grow && v > 0.f) {
      int b = (int)fminf(v * (float)NB, (float)(NB - 1));
      if (b >= T) {
        int pos = atomicAdd(&cnt, 1);
        if (pos < CAND) { cval[pos] = v; cidx[pos] = c; }
      }
    }
  }
  __syncthreads();
  const int n = min(cnt, CAND);
  // wave 0: iterative argmax over ~33 candidates
  if (tid < 64) {
    for (int it = 0; it < KF; ++it) {
      float bm = -1.f; int bp = -1;
      for (int e = tid; e < n; e += 64)
        if (cval[e] > bm) { bm = cval[e]; bp = e; }
      #pragma unroll
      for (int o = 32; o > 0; o >>= 1) {
        float ov = __shfl_down(bm, o);
        int   op = __shfl_down(bp, o);
        if (ov > bm) { bm = ov; bp = op; }
      }
      bm = __shfl(bm, 0); bp = __shfl(bp, 0);
      if (tid == 0) {
        if (bp >= 0) {
          fval[(size_t)grow * KF + it] = bm;
          fidx[(size_t)grow * KF + it] = cidx[bp];
          cval[bp] = -2.f;
        } else {                       // < KF positives: zero-weight self pick (no-op edge)
          fval[(size_t)grow * KF + it] = 0.f;
          fidx[(size_t)grow * KF + it] = grow;
        }
      }
    }
  }
}

// ---------------- 4. pixel kNN: one wave per pixel, register-resident distances ----------------
__global__ __launch_bounds__(256) void pix_topk_kernel(const float* __restrict__ im,
                                                       unsigned* __restrict__ pmask) {
  __shared__ float fr[HWP], fg[HWP], fb[HWP];
  const int tid = threadIdx.x;
  const int lane = tid & 63, wv = tid >> 6;
  const int b = blockIdx.x >> 8;                 // 4 pixels per block, same image
  const int p = ((blockIdx.x & 255) << 2) + wv;
  const float* imb = im + (size_t)b * 3 * HWP;
  for (int q = tid; q < HWP; q += 256) {
    fr[q] = imb[q]; fg[q] = imb[HWP + q]; fb[q] = imb[2 * HWP + q];
  }
  __syncthreads();
  const float pr = fr[p], pg = fg[p], pb = fb[p];
  const float px = (float)(p & 31) * (1.f / 31.f), py = (float)(p >> 5) * (1.f / 31.f);
  float d0[16], d1[16];
  #pragma unroll
  for (int i = 0; i < 16; ++i) {
    const int q = lane + (i << 6);
    // ((v+1)/2) differences = raw diff * 0.5; coordinate term is unscaled
    float dr = (fr[q] - pr) * 0.5f, dg = (fg[q] - pg) * 0.5f, db = (fb[q] - pb) * 0.5f;
    float drgb = dr * dr + dg * dg + db * db;
    float dx = (float)(q & 31) * (1.f / 31.f) - px;
    float dy = (float)(q >> 5) * (1.f / 31.f) - py;
    float cd = dx * dx + dy * dy;
    d0[i] = (q == p) ? 1e30f : drgb + 4.00f * cd;   // dw = 2.0
    d1[i] = (q == p) ? 1e30f : drgb + 0.01f * cd;   // dw = 0.1
  }
  const int mrow = (b << 10) + p;
  auto doPass = [&](float (&dd)[16]) {
    for (int it = 0; it < KP; ++it) {
      float bm = 1e30f; int bq = 0;
      #pragma unroll
      for (int i = 0; i < 16; ++i) {
        const int q = lane + (i << 6);
        if (dd[i] < bm) { bm = dd[i]; bq = q; }
      }
      #pragma unroll
      for (int o = 32; o > 0; o >>= 1) {
        float ov = __shfl_down(bm, o);
        int   oq = __shfl_down(bq, o);
        if (ov < bm) { bm = ov; bq = oq; }
      }
      bq = __shfl(bq, 0);
      if (lane == 0) {
        atomicOr(&pmask[(size_t)mrow * 32 + (bq >> 5)], 1u << (bq & 31));
        atomicOr(&pmask[((size_t)((b << 10) + bq)) * 32 + (p >> 5)], 1u << (p & 31));
      }
      #pragma unroll
      for (int i = 0; i < 16; ++i)
        if (lane + (i << 6) == bq) dd[i] = 1e30f;
    }
  };
  doPass(d0);
  doPass(d1);
}

// ---------------- 5. degrees -> rsqrt ----------------
__global__ void pix_deg_kernel(const unsigned* __restrict__ pmask, float* __restrict__ d2r) {
  int m = blockIdx.x * blockDim.x + threadIdx.x;
  if (m >= MT) return;
  int deg = 0;
  for (int w = 0; w < 32; ++w) deg += __popc(pmask[(size_t)m * 32 + w]);
  d2r[m] = (deg > 0) ? rsqrtf((float)deg) : 0.f;
}

__global__ void feat_deg_kernel(const int* __restrict__ fidx, const float* __restrict__ fval,
                                float* __restrict__ frow) {
  int m = blockIdx.x * blockDim.x + threadIdx.x;
  if (m >= MT) return;
  float s = 0.f;
  for (int k = 0; k < KF; ++k) {
    float v = fval[m * KF + k];
    s += v;
    atomicAdd(&frow[fidx[m * KF + k]], 0.5f * v);
  }
  atomicAdd(&frow[m], 0.5f * s);
}

__global__ void feat_rsqrt_kernel(const float* __restrict__ frow, float* __restrict__ dfeat) {
  int m = blockIdx.x * blockDim.x + threadIdx.x;
  if (m >= MT) return;
  float s = frow[m];
  dfeat[m] = (s > 0.f) ? rsqrtf(s) : 0.f;
}

// ---------------- 6. gP = gram_feat @ Psi'  (sparse scatter/gather, atomics) ----------------
__global__ __launch_bounds__(64) void gp_feat_kernel(const int* __restrict__ fidx,
                                                     const float* __restrict__ fval,
                                                     const float* __restrict__ dfeat,
                                                     const float* __restrict__ Psi,
                                                     float* __restrict__ gP) {
  const int j = blockIdx.x;
  const int t = threadIdx.x;
  const float pj = Psi[(size_t)j * KD + t] * SQT;
  const float dj = dfeat[j];
  float accj = 0.f;
  for (int k = 0; k < KF; ++k) {
    float v = fval[j * KF + k];
    int   c = fidx[j * KF + k];
    float wgt = 0.5f * v * dj * dfeat[c];
    accj += wgt * Psi[(size_t)c * KD + t] * SQT;
    atomicAdd(&gP[(size_t)c * KD + t], wgt * pj);
  }
  atomicAdd(&gP[(size_t)j * KD + t], accj);
}

// ---------------- 7. gP += PIXW * gram_pix @ Psi' ----------------
__global__ __launch_bounds__(64) void gp_pix_kernel(const unsigned* __restrict__ pmask,
                                                    const float* __restrict__ d2r,
                                                    const float* __restrict__ Psi,
                                                    float* __restrict__ gP) {
  __shared__ int list[HWP];
  __shared__ int cnt;
  const int m = blockIdx.x;
  const int t = threadIdx.x;
  const int b = m >> 10;
  if (t == 0) cnt = 0;
  __syncthreads();
  if (t < 32) {
    unsigned bits = pmask[(size_t)m * 32 + t];
    while (bits) {
      int bit = __ffs(bits) - 1;
      bits &= bits - 1;
      int pos = atomicAdd(&cnt, 1);
      list[pos] = t * 32 + bit;
    }
  }
  __syncthreads();
  const int n = cnt;
  float acc = 0.f;
  for (int e = 0; e < n; ++e) {
    int g = b * HWP + list[e];
    acc += d2r[g] * Psi[(size_t)g * KD + t];
  }
  gP[(size_t)m * KD + t] += PIXW * d2r[m] * acc * SQT;
}

// ---------------- 8. R = Psi'^T @ gP ----------------
__global__ __launch_bounds__(64) void r_kernel(const float* __restrict__ Psi,
                                               const float* __restrict__ gP,
                                               float* __restrict__ Rm) {
  const int a = blockIdx.x;
  const int t = threadIdx.x;
  const int mBeg = blockIdx.y * 512;
  float acc = 0.f;
  #pragma unroll 4
  for (int m = mBeg; m < mBeg + 512; ++m)
    acc += Psi[(size_t)m * KD + a] * gP[(size_t)m * KD + t];
  atomicAdd(&Rm[a * KD + t], acc * SQT);
}

// ---------------- 9. loss = -tr(R)/kd ; reg = sum(triu(R^2,1))/kd ----------------
__global__ __launch_bounds__(256) void final_kernel(const float* __restrict__ Rm,
                                                    float* __restrict__ out) {
  __shared__ float redt[256], redr[256];
  const int tid = threadIdx.x;
  float tr = 0.f, rg = 0.f;
  for (int e = tid; e < KD * KD; e += 256) {
    int a = e >> 6, c = e & 63;
    float v = Rm[e];
    if (a == c) tr += v;
    else if (c > a) rg += v * v;
  }
  redt[tid] = tr; redr[tid] = rg;
  __syncthreads();
  for (int o = 128; o > 0; o >>= 1) {
    if (tid < o) { redt[tid] += redt[tid + o]; redr[tid] += redr[tid + o]; }
    __syncthreads();
  }
  if (tid == 0) {
    out[0] = -redt[0] / (float)KD;
    out[1] = redr[0] / (float)KD;
  }
}

extern "C" void kernel_launch(void* const* d_in, const int* in_sizes, int n_in,
                              void* d_out, int out_size, void* d_ws, size_t ws_size,
                              hipStream_t stream) {
  const float* hl  = (const float*)d_in[0];   // [8,1024,768]
  const float* Psi = (const float*)d_in[1];   // [8,1024,64]
  const float* im  = (const float*)d_in[2];   // [8,3,32,32]
  float* out = (float*)d_out;

  char* ws = (char*)d_ws;
  size_t off = 0;
  auto alloc = [&](size_t bytes) -> void* {
    void* p = ws + off;
    off = (off + bytes + 255) & ~(size_t)255;
    return p;
  };
  __bf16*  Xhi   = (__bf16*)alloc((size_t)MT * DF * 2);
  __bf16*  Xlo   = (__bf16*)alloc((size_t)MT * DF * 2);
  float*   Sblk  = (float*)alloc((size_t)RB * MT * 4);
  int*     fidx  = (int*)alloc((size_t)MT * KF * 4);
  float*   fval  = (float*)alloc((size_t)MT * KF * 4);
  float*   frow  = (float*)alloc((size_t)MT * 4);
  float*   dfeat = (float*)alloc((size_t)MT * 4);
  unsigned* pmask = (unsigned*)alloc((size_t)MT * 32 * 4);
  float*   d2r   = (float*)alloc((size_t)MT * 4);
  float*   gP    = (float*)alloc((size_t)MT * KD * 4);
  float*   Rm    = (float*)alloc((size_t)KD * KD * 4);

  hipMemsetAsync(frow,  0, (size_t)MT * 4, stream);
  hipMemsetAsync(pmask, 0, (size_t)MT * 32 * 4, stream);
  hipMemsetAsync(gP,    0, (size_t)MT * KD * 4, stream);
  hipMemsetAsync(Rm,    0, (size_t)KD * KD * 4, stream);

  norm_split_kernel<<<MT, 256, 0, stream>>>(hl, Xhi, Xlo);
  pix_topk_kernel<<<MT / 4, 256, 0, stream>>>(im, pmask);
  pix_deg_kernel<<<MT / 256, 256, 0, stream>>>(pmask, d2r);

  for (int rb = 0; rb < MT / RB; ++rb) {
    gemm_kernel<<<dim3(MT / 128, RB / 128), 256, 0, stream>>>(Xhi, Xlo, Sblk, rb * RB);
    topk_kernel<<<RB, 256, 0, stream>>>(Sblk, fidx, fval, rb * RB);
  }

  feat_deg_kernel<<<MT / 256, 256, 0, stream>>>(fidx, fval, frow);
  feat_rsqrt_kernel<<<MT / 256, 256, 0, stream>>>(frow, dfeat);
  gp_feat_kernel<<<MT, 64, 0, stream>>>(fidx, fval, dfeat, Psi, gP);
  gp_pix_kernel<<<MT, 64, 0, stream>>>(pmask, d2r, Psi, gP);
  r_kernel<<<dim3(KD, 16), 64, 0, stream>>>(Psi, gP, Rm);
  final_kernel<<<1, 256, 0, stream>>>(Rm, out);
}

// Round 3
// 763.897 us; speedup vs baseline: 1.9365x; 1.4055x over previous
//
#include <hip/hip_runtime.h>
#include <hip/hip_bf16.h>
#include <math.h>

// Problem constants (Segmenter_65721589563708)
constexpr int MT  = 8192;   // bs*n
constexpr int DF  = 768;    // feature dim
constexpr int KD  = 64;     // kdim
constexpr int HWP = 1024;   // 32*32 pixels
constexpr int KF  = 32;     // feature kNN
constexpr int KP  = 10;     // pixel kNN
constexpr int RB  = 1024;   // GEMM row-block (fallback path)
#define SQT 3.16227766016837933f   // sqrt(T=10)
#define PIXW 0.05f

typedef __bf16 bf16x8 __attribute__((ext_vector_type(8)));
typedef float  f32x4  __attribute__((ext_vector_type(4)));

// ---------------- 1. normalize rows of X -> bf16 ----------------
__global__ __launch_bounds__(256) void norm_kernel(const float* __restrict__ X,
                                                   __bf16* __restrict__ Xb) {
  __shared__ float red[256];
  const int row = blockIdx.x, tid = threadIdx.x;
  const float* xr = X + (size_t)row * DF;
  float s = 0.f;
  for (int c = tid; c < DF; c += 256) { float v = xr[c]; s += v * v; }
  red[tid] = s; __syncthreads();
  for (int o = 128; o > 0; o >>= 1) { if (tid < o) red[tid] += red[tid + o]; __syncthreads(); }
  const float rn = rsqrtf(red[0]);
  __bf16* hr = Xb + (size_t)row * DF;
  for (int c = tid; c < DF; c += 256) hr[c] = (__bf16)(xr[c] * rn);
}

// ---------------- 2. S = Xb . Xb^T  (bf16 MFMA, XOR-swizzled LDS, m97 staging) ----------
// SYM=true: one dispatch over 2080 upper-tri 128x128 tiles, writes both mirrors into full S.
// SYM=false: fallback row-block path (grid dim3(64, RB/128)), writes local Sblk rows.
template <bool SYM>
__global__ __launch_bounds__(256) void gemm_kernel(const __bf16* __restrict__ Xb,
                                                   float* __restrict__ S, int rowBase) {
  __shared__ __bf16 As[128 * 64];
  __shared__ __bf16 Bs[128 * 64];
  const int tid = threadIdx.x;
  const int lane = tid & 63;
  const int wv = tid >> 6;
  const int wm = (wv & 1) * 64, wn = (wv >> 1) * 64;
  const int l15 = lane & 15, lq = lane >> 4;
  const int lr8 = lane >> 3, lc8 = lane & 7;   // staging: row-in-group, 16B chunk
  const int rsw = l15 & 7;                     // fragment-row swizzle key

  int m0, n0;
  if (SYM) {
    int L = blockIdx.x, ti = 0;
    while (L >= 64 - ti) { L -= 64 - ti; ++ti; }
    m0 = ti * 128;
    n0 = (ti + L) * 128;
  } else {
    m0 = rowBase + blockIdx.y * 128;
    n0 = blockIdx.x * 128;
  }

  f32x4 acc[4][4];
  #pragma unroll
  for (int i = 0; i < 4; ++i)
    #pragma unroll
    for (int j = 0; j < 4; ++j)
      #pragma unroll
      for (int r = 0; r < 4; ++r) acc[i][j][r] = 0.f;

  for (int kt = 0; kt < 12; ++kt) {
    const int col0 = kt * 64;
    const __bf16* Ag = Xb + (size_t)m0 * DF + col0;
    const __bf16* Bg = Xb + (size_t)n0 * DF + col0;
    // stage with k-chunk XOR swizzle on the SOURCE side: LDS(row, c) = global(row, c ^ (row&7))
    #pragma unroll
    for (int i = 0; i < 4; ++i) {
      const int r0 = (wv * 4 + i) * 8;         // 8 rows per issue, wave-uniform base
      const int csw = (lc8 ^ lr8) * 8;
      __builtin_amdgcn_global_load_lds(
          (const __attribute__((address_space(1))) void*)(Ag + (size_t)(r0 + lr8) * DF + csw),
          (__attribute__((address_space(3))) void*)(&As[r0 * 64]), 16, 0, 0);
      __builtin_amdgcn_global_load_lds(
          (const __attribute__((address_space(1))) void*)(Bg + (size_t)(r0 + lr8) * DF + csw),
          (__attribute__((address_space(3))) void*)(&Bs[r0 * 64]), 16, 0, 0);
    }
    __syncthreads();
    #pragma unroll
    for (int kk = 0; kk < 64; kk += 32) {
      bf16x8 af[4], bg[4];
      #pragma unroll
      for (int i = 0; i < 4; ++i)
        af[i] = *(const bf16x8*)(&As[(wm + i * 16 + l15) * 64 + ((((kk >> 3) + lq) ^ rsw) * 8)]);
      #pragma unroll
      for (int j = 0; j < 4; ++j)
        bg[j] = *(const bf16x8*)(&Bs[(wn + j * 16 + l15) * 64 + ((((kk >> 3) + lq) ^ rsw) * 8)]);
      #pragma unroll
      for (int i = 0; i < 4; ++i)
        #pragma unroll
        for (int j = 0; j < 4; ++j)
          acc[i][j] = __builtin_amdgcn_mfma_f32_16x16x32_bf16(af[i], bg[j], acc[i][j], 0, 0, 0);
    }
    __syncthreads();
  }
  // C/D layout: col = lane&15, row = (lane>>4)*4 + reg   [m89/m91 verified]
  #pragma unroll
  for (int i = 0; i < 4; ++i)
    #pragma unroll
    for (int j = 0; j < 4; ++j)
      #pragma unroll
      for (int r = 0; r < 4; ++r) {
        const int lrow = m0 + wm + i * 16 + lq * 4 + r;
        const int col  = n0 + wn + j * 16 + l15;
        const float v = acc[i][j][r];
        if (SYM) {
          S[(size_t)lrow * MT + col] = v;
          S[(size_t)col * MT + lrow] = v;   // mirror; diag tiles: bitwise-identical benign race
        } else {
          S[(size_t)(lrow - rowBase) * MT + col] = v;
        }
      }
}

// ---------------- 3. top-32 per row via histogram threshold + candidate select ----------------
constexpr int NB   = 1024;   // histogram bins over [0,1]
constexpr int CAND = 2048;   // candidate cap (expected ~33 with random data)

__global__ __launch_bounds__(256) void topk_kernel(const float* __restrict__ Sblk,
                                                   int* __restrict__ fidx,
                                                   float* __restrict__ fval, int rowBase) {
  __shared__ int   hist[NB];
  __shared__ int   chunk[256];
  __shared__ float cval[CAND];
  __shared__ int   cidx[CAND];
  __shared__ int   cnt, tbin;
  const int tid = threadIdx.x;
  const int rl = blockIdx.x;
  const int grow = rowBase + rl;
  const float* srow = Sblk + (size_t)rl * MT;
  #pragma unroll
  for (int i = tid; i < NB; i += 256) hist[i] = 0;
  if (tid == 0) cnt = 0;
  __syncthreads();
  // pass 1: histogram of positive, non-diagonal values
  for (int c = tid; c < MT; c += 256) {
    float v = srow[c];
    if (c != grow && v > 0.f) {
      int b = (int)fminf(v * (float)NB, (float)(NB - 1));
      atomicAdd(&hist[b], 1);
    }
  }
  __syncthreads();
  { int s = 0;
    #pragma unroll
    for (int i = 0; i < 4; ++i) s += hist[tid * 4 + i];
    chunk[tid] = s; }
  __syncthreads();
  if (tid == 0) {
    int acc = 0, ch = 255;
    for (; ch > 0; --ch) {
      if (acc + chunk[ch] >= KF) break;
      acc += chunk[ch];
    }
    int b = ch * 4 + 3;
    for (; b > ch * 4; --b) {
      if (acc + hist[b] >= KF) break;
      acc += hist[b];
    }
    tbin = b;   // bins >= tbin hold >= KF values (or everything if row degenerate)
  }
  __syncthreads();
  const int T = tbin;
  // pass 2: collect candidates in bins >= T
  for (int c = tid; c < MT; c += 256) {
    float v = srow[c];
    if (c != grow && v > 0.f) {
      int b = (int)fminf(v * (float)NB, (float)(NB - 1));
      if (b >= T) {
        int pos = atomicAdd(&cnt, 1);
        if (pos < CAND) { cval[pos] = v; cidx[pos] = c; }
      }
    }
  }
  __syncthreads();
  const int n = min(cnt, CAND);
  // wave 0: iterative argmax over ~33 candidates
  if (tid < 64) {
    for (int it = 0; it < KF; ++it) {
      float bm = -1.f; int bp = -1;
      for (int e = tid; e < n; e += 64)
        if (cval[e] > bm) { bm = cval[e]; bp = e; }
      #pragma unroll
      for (int o = 32; o > 0; o >>= 1) {
        float ov = __shfl_down(bm, o);
        int   op = __shfl_down(bp, o);
        if (ov > bm) { bm = ov; bp = op; }
      }
      bm = __shfl(bm, 0); bp = __shfl(bp, 0);
      if (tid == 0) {
        if (bp >= 0) {
          fval[(size_t)grow * KF + it] = bm;
          fidx[(size_t)grow * KF + it] = cidx[bp];
          cval[bp] = -2.f;
        } else {                       // < KF positives: zero-weight self pick (no-op edge)
          fval[(size_t)grow * KF + it] = 0.f;
          fidx[(size_t)grow * KF + it] = grow;
        }
      }
    }
  }
}

// ---------------- 4. pixel kNN: one wave per pixel, register-resident distances ----------------
__global__ __launch_bounds__(256) void pix_topk_kernel(const float* __restrict__ im,
                                                       unsigned* __restrict__ pmask) {
  __shared__ float fr[HWP], fg[HWP], fb[HWP];
  const int tid = threadIdx.x;
  const int lane = tid & 63, wv = tid >> 6;
  const int b = blockIdx.x >> 8;                 // 4 pixels per block, same image
  const int p = ((blockIdx.x & 255) << 2) + wv;
  const float* imb = im + (size_t)b * 3 * HWP;
  for (int q = tid; q < HWP; q += 256) {
    fr[q] = imb[q]; fg[q] = imb[HWP + q]; fb[q] = imb[2 * HWP + q];
  }
  __syncthreads();
  const float pr = fr[p], pg = fg[p], pb = fb[p];
  const float px = (float)(p & 31) * (1.f / 31.f), py = (float)(p >> 5) * (1.f / 31.f);
  float d0[16], d1[16];
  #pragma unroll
  for (int i = 0; i < 16; ++i) {
    const int q = lane + (i << 6);
    // ((v+1)/2) differences = raw diff * 0.5; coordinate term is unscaled
    float dr = (fr[q] - pr) * 0.5f, dg = (fg[q] - pg) * 0.5f, db = (fb[q] - pb) * 0.5f;
    float drgb = dr * dr + dg * dg + db * db;
    float dx = (float)(q & 31) * (1.f / 31.f) - px;
    float dy = (float)(q >> 5) * (1.f / 31.f) - py;
    float cd = dx * dx + dy * dy;
    d0[i] = (q == p) ? 1e30f : drgb + 4.00f * cd;   // dw = 2.0
    d1[i] = (q == p) ? 1e30f : drgb + 0.01f * cd;   // dw = 0.1
  }
  const int mrow = (b << 10) + p;
  auto doPass = [&](float (&dd)[16]) {
    for (int it = 0; it < KP; ++it) {
      float bm = 1e30f; int bq = 0;
      #pragma unroll
      for (int i = 0; i < 16; ++i) {
        const int q = lane + (i << 6);
        if (dd[i] < bm) { bm = dd[i]; bq = q; }
      }
      #pragma unroll
      for (int o = 32; o > 0; o >>= 1) {
        float ov = __shfl_down(bm, o);
        int   oq = __shfl_down(bq, o);
        if (ov < bm) { bm = ov; bq = oq; }
      }
      bq = __shfl(bq, 0);
      if (lane == 0) {
        atomicOr(&pmask[(size_t)mrow * 32 + (bq >> 5)], 1u << (bq & 31));
        atomicOr(&pmask[((size_t)((b << 10) + bq)) * 32 + (p >> 5)], 1u << (p & 31));
      }
      #pragma unroll
      for (int i = 0; i < 16; ++i)
        if (lane + (i << 6) == bq) dd[i] = 1e30f;
    }
  };
  doPass(d0);
  doPass(d1);
}

// ---------------- 5. degrees -> rsqrt ----------------
__global__ void pix_deg_kernel(const unsigned* __restrict__ pmask, float* __restrict__ d2r) {
  int m = blockIdx.x * blockDim.x + threadIdx.x;
  if (m >= MT) return;
  int deg = 0;
  for (int w = 0; w < 32; ++w) deg += __popc(pmask[(size_t)m * 32 + w]);
  d2r[m] = (deg > 0) ? rsqrtf((float)deg) : 0.f;
}

__global__ void feat_deg_kernel(const int* __restrict__ fidx, const float* __restrict__ fval,
                                float* __restrict__ frow) {
  int m = blockIdx.x * blockDim.x + threadIdx.x;
  if (m >= MT) return;
  float s = 0.f;
  for (int k = 0; k < KF; ++k) {
    float v = fval[m * KF + k];
    s += v;
    atomicAdd(&frow[fidx[m * KF + k]], 0.5f * v);
  }
  atomicAdd(&frow[m], 0.5f * s);
}

__global__ void feat_rsqrt_kernel(const float* __restrict__ frow, float* __restrict__ dfeat) {
  int m = blockIdx.x * blockDim.x + threadIdx.x;
  if (m >= MT) return;
  float s = frow[m];
  dfeat[m] = (s > 0.f) ? rsqrtf(s) : 0.f;
}

// ---------------- 6. gP = gram_feat @ Psi'  (sparse scatter/gather, atomics) ----------------
__global__ __launch_bounds__(64) void gp_feat_kernel(const int* __restrict__ fidx,
                                                     const float* __restrict__ fval,
                                                     const float* __restrict__ dfeat,
                                                     const float* __restrict__ Psi,
                                                     float* __restrict__ gP) {
  const int j = blockIdx.x;
  const int t = threadIdx.x;
  const float pj = Psi[(size_t)j * KD + t] * SQT;
  const float dj = dfeat[j];
  float accj = 0.f;
  for (int k = 0; k < KF; ++k) {
    float v = fval[j * KF + k];
    int   c = fidx[j * KF + k];
    float wgt = 0.5f * v * dj * dfeat[c];
    accj += wgt * Psi[(size_t)c * KD + t] * SQT;
    atomicAdd(&gP[(size_t)c * KD + t], wgt * pj);
  }
  atomicAdd(&gP[(size_t)j * KD + t], accj);
}

// ---------------- 7. gP += PIXW * gram_pix @ Psi' ----------------
__global__ __launch_bounds__(64) void gp_pix_kernel(const unsigned* __restrict__ pmask,
                                                    const float* __restrict__ d2r,
                                                    const float* __restrict__ Psi,
                                                    float* __restrict__ gP) {
  __shared__ int list[HWP];
  __shared__ int cnt;
  const int m = blockIdx.x;
  const int t = threadIdx.x;
  const int b = m >> 10;
  if (t == 0) cnt = 0;
  __syncthreads();
  if (t < 32) {
    unsigned bits = pmask[(size_t)m * 32 + t];
    while (bits) {
      int bit = __ffs(bits) - 1;
      bits &= bits - 1;
      int pos = atomicAdd(&cnt, 1);
      list[pos] = t * 32 + bit;
    }
  }
  __syncthreads();
  const int n = cnt;
  float acc = 0.f;
  for (int e = 0; e < n; ++e) {
    int g = b * HWP + list[e];
    acc += d2r[g] * Psi[(size_t)g * KD + t];
  }
  gP[(size_t)m * KD + t] += PIXW * d2r[m] * acc * SQT;
}

// ---------------- 8. R = Psi'^T @ gP ----------------
__global__ __launch_bounds__(64) void r_kernel(const float* __restrict__ Psi,
                                               const float* __restrict__ gP,
                                               float* __restrict__ Rm) {
  const int a = blockIdx.x;
  const int t = threadIdx.x;
  const int mBeg = blockIdx.y * 512;
  float acc = 0.f;
  #pragma unroll 4
  for (int m = mBeg; m < mBeg + 512; ++m)
    acc += Psi[(size_t)m * KD + a] * gP[(size_t)m * KD + t];
  atomicAdd(&Rm[a * KD + t], acc * SQT);
}

// ---------------- 9. loss = -tr(R)/kd ; reg = sum(triu(R^2,1))/kd ----------------
__global__ __launch_bounds__(256) void final_kernel(const float* __restrict__ Rm,
                                                    float* __restrict__ out) {
  __shared__ float redt[256], redr[256];
  const int tid = threadIdx.x;
  float tr = 0.f, rg = 0.f;
  for (int e = tid; e < KD * KD; e += 256) {
    int a = e >> 6, c = e & 63;
    float v = Rm[e];
    if (a == c) tr += v;
    else if (c > a) rg += v * v;
  }
  redt[tid] = tr; redr[tid] = rg;
  __syncthreads();
  for (int o = 128; o > 0; o >>= 1) {
    if (tid < o) { redt[tid] += redt[tid + o]; redr[tid] += redr[tid + o]; }
    __syncthreads();
  }
  if (tid == 0) {
    out[0] = -redt[0] / (float)KD;
    out[1] = redr[0] / (float)KD;
  }
}

extern "C" void kernel_launch(void* const* d_in, const int* in_sizes, int n_in,
                              void* d_out, int out_size, void* d_ws, size_t ws_size,
                              hipStream_t stream) {
  const float* hl  = (const float*)d_in[0];   // [8,1024,768]
  const float* Psi = (const float*)d_in[1];   // [8,1024,64]
  const float* im  = (const float*)d_in[2];   // [8,3,32,32]
  float* out = (float*)d_out;

  // small-buffer footprint (everything except S)
  const size_t smallBytes = (size_t)MT * DF * 2 + (size_t)MT * KF * 8 + (size_t)MT * 4 * 3 +
                            (size_t)MT * 32 * 4 + (size_t)MT * KD * 4 + (size_t)KD * KD * 4 +
                            16 * 4096;
  const bool fullS = ws_size >= (size_t)MT * MT * 4 + smallBytes;

  char* ws = (char*)d_ws;
  size_t off = 0;
  auto alloc = [&](size_t bytes) -> void* {
    void* p = ws + off;
    off = (off + bytes + 255) & ~(size_t)255;
    return p;
  };
  float*   S     = (float*)alloc(fullS ? (size_t)MT * MT * 4 : (size_t)RB * MT * 4);
  __bf16*  Xb    = (__bf16*)alloc((size_t)MT * DF * 2);
  int*     fidx  = (int*)alloc((size_t)MT * KF * 4);
  float*   fval  = (float*)alloc((size_t)MT * KF * 4);
  float*   frow  = (float*)alloc((size_t)MT * 4);
  float*   dfeat = (float*)alloc((size_t)MT * 4);
  unsigned* pmask = (unsigned*)alloc((size_t)MT * 32 * 4);
  float*   d2r   = (float*)alloc((size_t)MT * 4);
  float*   gP    = (float*)alloc((size_t)MT * KD * 4);
  float*   Rm    = (float*)alloc((size_t)KD * KD * 4);

  hipMemsetAsync(frow,  0, (size_t)MT * 4, stream);
  hipMemsetAsync(pmask, 0, (size_t)MT * 32 * 4, stream);
  hipMemsetAsync(gP,    0, (size_t)MT * KD * 4, stream);
  hipMemsetAsync(Rm,    0, (size_t)KD * KD * 4, stream);

  norm_kernel<<<MT, 256, 0, stream>>>(hl, Xb);
  pix_topk_kernel<<<MT / 4, 256, 0, stream>>>(im, pmask);
  pix_deg_kernel<<<MT / 256, 256, 0, stream>>>(pmask, d2r);

  if (fullS) {
    gemm_kernel<true><<<2080, 256, 0, stream>>>(Xb, S, 0);
    topk_kernel<<<MT, 256, 0, stream>>>(S, fidx, fval, 0);
  } else {
    for (int rb = 0; rb < MT / RB; ++rb) {
      gemm_kernel<false><<<dim3(MT / 128, RB / 128), 256, 0, stream>>>(Xb, S, rb * RB);
      topk_kernel<<<RB, 256, 0, stream>>>(S, fidx, fval, rb * RB);
    }
  }

  feat_deg_kernel<<<MT / 256, 256, 0, stream>>>(fidx, fval, frow);
  feat_rsqrt_kernel<<<MT / 256, 256, 0, stream>>>(frow, dfeat);
  gp_feat_kernel<<<MT, 64, 0, stream>>>(fidx, fval, dfeat, Psi, gP);
  gp_pix_kernel<<<MT, 64, 0, stream>>>(pmask, d2r, Psi, gP);
  r_kernel<<<dim3(KD, 16), 64, 0, stream>>>(Psi, gP, Rm);
  final_kernel<<<1, 256, 0, stream>>>(Rm, out);
}

// Round 4
// 716.899 us; speedup vs baseline: 2.0634x; 1.0656x over previous
//
#include <hip/hip_runtime.h>
#include <hip/hip_bf16.h>
#include <math.h>

// Problem constants (Segmenter_65721589563708)
constexpr int MT  = 8192;   // bs*n
constexpr int DF  = 768;    // feature dim
constexpr int KD  = 64;     // kdim
constexpr int HWP = 1024;   // 32*32 pixels
constexpr int KF  = 32;     // feature kNN
constexpr int KP  = 10;     // pixel kNN
constexpr int RB  = 1024;   // GEMM row-block (fallback path)
#define SQT 3.16227766016837933f   // sqrt(T=10)
#define PIXW 0.05f

typedef __bf16 bf16x8 __attribute__((ext_vector_type(8)));
typedef float  f32x4  __attribute__((ext_vector_type(4)));

// ---------------- 1. normalize rows of X -> bf16 ----------------
__global__ __launch_bounds__(256) void norm_kernel(const float* __restrict__ X,
                                                   __bf16* __restrict__ Xb) {
  __shared__ float red[256];
  const int row = blockIdx.x, tid = threadIdx.x;
  const float* xr = X + (size_t)row * DF;
  float s = 0.f;
  for (int c = tid; c < DF; c += 256) { float v = xr[c]; s += v * v; }
  red[tid] = s; __syncthreads();
  for (int o = 128; o > 0; o >>= 1) { if (tid < o) red[tid] += red[tid + o]; __syncthreads(); }
  const float rn = rsqrtf(red[0]);
  __bf16* hr = Xb + (size_t)row * DF;
  for (int c = tid; c < DF; c += 256) hr[c] = (__bf16)(xr[c] * rn);
}

// ---------------- 2. S = Xb . Xb^T  (bf16 MFMA, XOR-swizzled LDS, m97 staging) ----------
template <bool SYM>
__global__ __launch_bounds__(256) void gemm_kernel(const __bf16* __restrict__ Xb,
                                                   float* __restrict__ S, int rowBase) {
  __shared__ __bf16 As[128 * 64];
  __shared__ __bf16 Bs[128 * 64];
  const int tid = threadIdx.x;
  const int lane = tid & 63;
  const int wv = tid >> 6;
  const int wm = (wv & 1) * 64, wn = (wv >> 1) * 64;
  const int l15 = lane & 15, lq = lane >> 4;
  const int lr8 = lane >> 3, lc8 = lane & 7;   // staging: row-in-group, 16B chunk
  const int rsw = l15 & 7;                     // fragment-row swizzle key

  int m0, n0;
  if (SYM) {
    int L = blockIdx.x, ti = 0;
    while (L >= 64 - ti) { L -= 64 - ti; ++ti; }
    m0 = ti * 128;
    n0 = (ti + L) * 128;
  } else {
    m0 = rowBase + blockIdx.y * 128;
    n0 = blockIdx.x * 128;
  }

  f32x4 acc[4][4];
  #pragma unroll
  for (int i = 0; i < 4; ++i)
    #pragma unroll
    for (int j = 0; j < 4; ++j)
      #pragma unroll
      for (int r = 0; r < 4; ++r) acc[i][j][r] = 0.f;

  for (int kt = 0; kt < 12; ++kt) {
    const int col0 = kt * 64;
    const __bf16* Ag = Xb + (size_t)m0 * DF + col0;
    const __bf16* Bg = Xb + (size_t)n0 * DF + col0;
    #pragma unroll
    for (int i = 0; i < 4; ++i) {
      const int r0 = (wv * 4 + i) * 8;         // 8 rows per issue, wave-uniform base
      const int csw = (lc8 ^ lr8) * 8;
      __builtin_amdgcn_global_load_lds(
          (const __attribute__((address_space(1))) void*)(Ag + (size_t)(r0 + lr8) * DF + csw),
          (__attribute__((address_space(3))) void*)(&As[r0 * 64]), 16, 0, 0);
      __builtin_amdgcn_global_load_lds(
          (const __attribute__((address_space(1))) void*)(Bg + (size_t)(r0 + lr8) * DF + csw),
          (__attribute__((address_space(3))) void*)(&Bs[r0 * 64]), 16, 0, 0);
    }
    __syncthreads();
    #pragma unroll
    for (int kk = 0; kk < 64; kk += 32) {
      bf16x8 af[4], bg[4];
      #pragma unroll
      for (int i = 0; i < 4; ++i)
        af[i] = *(const bf16x8*)(&As[(wm + i * 16 + l15) * 64 + ((((kk >> 3) + lq) ^ rsw) * 8)]);
      #pragma unroll
      for (int j = 0; j < 4; ++j)
        bg[j] = *(const bf16x8*)(&Bs[(wn + j * 16 + l15) * 64 + ((((kk >> 3) + lq) ^ rsw) * 8)]);
      #pragma unroll
      for (int i = 0; i < 4; ++i)
        #pragma unroll
        for (int j = 0; j < 4; ++j)
          acc[i][j] = __builtin_amdgcn_mfma_f32_16x16x32_bf16(af[i], bg[j], acc[i][j], 0, 0, 0);
    }
    __syncthreads();
  }
  #pragma unroll
  for (int i = 0; i < 4; ++i)
    #pragma unroll
    for (int j = 0; j < 4; ++j)
      #pragma unroll
      for (int r = 0; r < 4; ++r) {
        const int lrow = m0 + wm + i * 16 + lq * 4 + r;
        const int col  = n0 + wn + j * 16 + l15;
        const float v = acc[i][j][r];
        if (SYM) {
          S[(size_t)lrow * MT + col] = v;
          S[(size_t)col * MT + lrow] = v;   // mirror; diag tiles: bitwise-identical benign race
        } else {
          S[(size_t)(lrow - rowBase) * MT + col] = v;
        }
      }
}

// ---------------- 3. top-32 per row: single HBM pass, register-resident values ----------------
constexpr int NB   = 1024;   // histogram bins over [0,1]
constexpr int CAND = 2048;   // candidate cap (expected ~33 with random data)
constexpr int VPT  = MT / 256;  // 32 values per thread

__global__ __launch_bounds__(256) void topk_kernel(const float* __restrict__ Sblk,
                                                   int* __restrict__ fidx,
                                                   float* __restrict__ fval, int rowBase) {
  __shared__ int   hist[NB];
  __shared__ int   chunk[256];
  __shared__ float cval[CAND];
  __shared__ int   cidx[CAND];
  __shared__ int   cnt, tbin;
  const int tid = threadIdx.x;
  const int rl = blockIdx.x;
  const int grow = rowBase + rl;
  const float* srow = Sblk + (size_t)rl * MT;
  float vals[VPT];
  #pragma unroll
  for (int i = tid; i < NB; i += 256) hist[i] = 0;
  if (tid == 0) cnt = 0;
  __syncthreads();
  // pass 1: load row into registers, histogram positive non-diagonal values
  #pragma unroll
  for (int i = 0; i < VPT; ++i) {
    const int c = tid + i * 256;
    float v = srow[c];
    if (c == grow) v = -1.f;
    vals[i] = v;
    if (v > 0.f) {
      int b = (int)fminf(v * (float)NB, (float)(NB - 1));
      atomicAdd(&hist[b], 1);
    }
  }
  __syncthreads();
  { int s = 0;
    #pragma unroll
    for (int i = 0; i < 4; ++i) s += hist[tid * 4 + i];
    chunk[tid] = s; }
  __syncthreads();
  if (tid == 0) {
    int acc = 0, ch = 255;
    for (; ch > 0; --ch) {
      if (acc + chunk[ch] >= KF) break;
      acc += chunk[ch];
    }
    int b = ch * 4 + 3;
    for (; b > ch * 4; --b) {
      if (acc + hist[b] >= KF) break;
      acc += hist[b];
    }
    tbin = b;
  }
  __syncthreads();
  const float thr = (float)tbin * (1.f / (float)NB);
  // pass 2: collect candidates from registers
  #pragma unroll
  for (int i = 0; i < VPT; ++i) {
    float v = vals[i];
    if (v > 0.f && v >= thr) {
      int pos = atomicAdd(&cnt, 1);
      if (pos < CAND) { cval[pos] = v; cidx[pos] = tid + i * 256; }
    }
  }
  __syncthreads();
  const int n = min(cnt, CAND);
  // wave 0: iterative argmax over ~33 candidates
  if (tid < 64) {
    for (int it = 0; it < KF; ++it) {
      float bm = -1.f; int bp = -1;
      for (int e = tid; e < n; e += 64)
        if (cval[e] > bm) { bm = cval[e]; bp = e; }
      #pragma unroll
      for (int o = 32; o > 0; o >>= 1) {
        float ov = __shfl_down(bm, o);
        int   op = __shfl_down(bp, o);
        if (ov > bm) { bm = ov; bp = op; }
      }
      bm = __shfl(bm, 0); bp = __shfl(bp, 0);
      if (tid == 0) {
        if (bp >= 0) {
          fval[(size_t)grow * KF + it] = bm;
          fidx[(size_t)grow * KF + it] = cidx[bp];
          cval[bp] = -2.f;
        } else {
          fval[(size_t)grow * KF + it] = 0.f;
          fidx[(size_t)grow * KF + it] = grow;
        }
      }
    }
  }
}

// ---------------- 4. pixel kNN: one wave per pixel, register-resident distances ----------------
__global__ __launch_bounds__(256) void pix_topk_kernel(const float* __restrict__ im,
                                                       unsigned* __restrict__ pmask) {
  __shared__ float fr[HWP], fg[HWP], fb[HWP];
  const int tid = threadIdx.x;
  const int lane = tid & 63, wv = tid >> 6;
  const int b = blockIdx.x >> 8;
  const int p = ((blockIdx.x & 255) << 2) + wv;
  const float* imb = im + (size_t)b * 3 * HWP;
  for (int q = tid; q < HWP; q += 256) {
    fr[q] = imb[q]; fg[q] = imb[HWP + q]; fb[q] = imb[2 * HWP + q];
  }
  __syncthreads();
  const float pr = fr[p], pg = fg[p], pb = fb[p];
  const float px = (float)(p & 31) * (1.f / 31.f), py = (float)(p >> 5) * (1.f / 31.f);
  float d0[16], d1[16];
  #pragma unroll
  for (int i = 0; i < 16; ++i) {
    const int q = lane + (i << 6);
    float dr = (fr[q] - pr) * 0.5f, dg = (fg[q] - pg) * 0.5f, db = (fb[q] - pb) * 0.5f;
    float drgb = dr * dr + dg * dg + db * db;
    float dx = (float)(q & 31) * (1.f / 31.f) - px;
    float dy = (float)(q >> 5) * (1.f / 31.f) - py;
    float cd = dx * dx + dy * dy;
    d0[i] = (q == p) ? 1e30f : drgb + 4.00f * cd;   // dw = 2.0
    d1[i] = (q == p) ? 1e30f : drgb + 0.01f * cd;   // dw = 0.1
  }
  const int mrow = (b << 10) + p;
  auto doPass = [&](float (&dd)[16]) {
    for (int it = 0; it < KP; ++it) {
      float bm = 1e30f; int bq = 0;
      #pragma unroll
      for (int i = 0; i < 16; ++i) {
        const int q = lane + (i << 6);
        if (dd[i] < bm) { bm = dd[i]; bq = q; }
      }
      #pragma unroll
      for (int o = 32; o > 0; o >>= 1) {
        float ov = __shfl_down(bm, o);
        int   oq = __shfl_down(bq, o);
        if (ov < bm) { bm = ov; bq = oq; }
      }
      bq = __shfl(bq, 0);
      if (lane == 0) {
        atomicOr(&pmask[(size_t)mrow * 32 + (bq >> 5)], 1u << (bq & 31));
        atomicOr(&pmask[((size_t)((b << 10) + bq)) * 32 + (p >> 5)], 1u << (p & 31));
      }
      #pragma unroll
      for (int i = 0; i < 16; ++i)
        if (lane + (i << 6) == bq) dd[i] = 1e30f;
    }
  };
  doPass(d0);
  doPass(d1);
}

// ---------------- 5. feature degrees (row sums of (res+res^T)/2) ----------------
__global__ void feat_deg_kernel(const int* __restrict__ fidx, const float* __restrict__ fval,
                                float* __restrict__ frow) {
  int m = blockIdx.x * blockDim.x + threadIdx.x;
  if (m >= MT) return;
  float s = 0.f;
  for (int k = 0; k < KF; ++k) {
    float v = fval[m * KF + k];
    s += v;
    atomicAdd(&frow[fidx[m * KF + k]], 0.5f * v);
  }
  atomicAdd(&frow[m], 0.5f * s);
}

// ---------------- 6. prep: U = dfeat*sqrt(T)*Psi, V = d2r*sqrt(T)*Psi ----------------
__global__ __launch_bounds__(64) void prep_kernel(const float* __restrict__ frow,
                                                  const unsigned* __restrict__ pmask,
                                                  const float* __restrict__ Psi,
                                                  float* __restrict__ U,
                                                  float* __restrict__ V) {
  const int m = blockIdx.x, t = threadIdx.x;
  int pd = (t < 32) ? __popc(pmask[(size_t)m * 32 + t]) : 0;
  #pragma unroll
  for (int o = 16; o > 0; o >>= 1) pd += __shfl_down(pd, o);
  pd = __shfl(pd, 0);
  const float fr = frow[m];
  const float df = (fr > 0.f) ? rsqrtf(fr) : 0.f;
  const float dp = (pd > 0) ? rsqrtf((float)pd) : 0.f;
  const float p = Psi[(size_t)m * KD + t] * SQT;
  U[(size_t)m * KD + t] = df * p;
  V[(size_t)m * KD + t] = dp * p;
}

// ---------------- 7. Wf[j] = sum_k 0.5*v_jk * U[c_jk]   (pure gather, no atomics) ---------
__global__ __launch_bounds__(64) void gather_feat_kernel(const int* __restrict__ fidx,
                                                         const float* __restrict__ fval,
                                                         const float* __restrict__ U,
                                                         float* __restrict__ Wf) {
  const int j = blockIdx.x, t = threadIdx.x;
  float acc = 0.f;
  for (int k = 0; k < KF; ++k) {
    float v = fval[j * KF + k];
    int   c = fidx[j * KF + k];
    acc += 0.5f * v * U[(size_t)c * KD + t];
  }
  Wf[(size_t)j * KD + t] = acc;
}

// ---------------- 8. W2[m] = sum_{q in adj(m)} V[q]   (pure gather) ----------------
__global__ __launch_bounds__(64) void gather_pix_kernel(const unsigned* __restrict__ pmask,
                                                        const float* __restrict__ V,
                                                        float* __restrict__ W2) {
  __shared__ int list[HWP];
  __shared__ int cnt;
  const int m = blockIdx.x;
  const int t = threadIdx.x;
  const int b = m >> 10;
  if (t == 0) cnt = 0;
  __syncthreads();
  if (t < 32) {
    unsigned bits = pmask[(size_t)m * 32 + t];
    while (bits) {
      int bit = __ffs(bits) - 1;
      bits &= bits - 1;
      int pos = atomicAdd(&cnt, 1);
      list[pos] = t * 32 + bit;
    }
  }
  __syncthreads();
  const int n = cnt;
  float acc = 0.f;
  for (int e = 0; e < n; ++e)
    acc += V[(size_t)(b * HWP + list[e]) * KD + t];
  W2[(size_t)m * KD + t] = acc;
}

// ---------------- 9. Rm += scale * (L^T Wm)  [+ transpose if sym] ----------------
__global__ __launch_bounds__(64) void rmat_kernel(const float* __restrict__ L,
                                                  const float* __restrict__ Wm,
                                                  float* __restrict__ Rm,
                                                  float scale, int sym) {
  const int a = blockIdx.x;
  const int t = threadIdx.x;
  const int mBeg = blockIdx.y * 512;
  float acc = 0.f;
  #pragma unroll 4
  for (int m = mBeg; m < mBeg + 512; ++m)
    acc += L[(size_t)m * KD + a] * Wm[(size_t)m * KD + t];
  acc *= scale;
  atomicAdd(&Rm[a * KD + t], acc);
  if (sym) atomicAdd(&Rm[t * KD + a], acc);
}

// ---------------- 10. loss = -tr(R)/kd ; reg = sum(triu(R^2,1))/kd ----------------
__global__ __launch_bounds__(256) void final_kernel(const float* __restrict__ Rm,
                                                    float* __restrict__ out) {
  __shared__ float redt[256], redr[256];
  const int tid = threadIdx.x;
  float tr = 0.f, rg = 0.f;
  for (int e = tid; e < KD * KD; e += 256) {
    int a = e >> 6, c = e & 63;
    float v = Rm[e];
    if (a == c) tr += v;
    else if (c > a) rg += v * v;
  }
  redt[tid] = tr; redr[tid] = rg;
  __syncthreads();
  for (int o = 128; o > 0; o >>= 1) {
    if (tid < o) { redt[tid] += redt[tid + o]; redr[tid] += redr[tid + o]; }
    __syncthreads();
  }
  if (tid == 0) {
    out[0] = -redt[0] / (float)KD;
    out[1] = redr[0] / (float)KD;
  }
}

extern "C" void kernel_launch(void* const* d_in, const int* in_sizes, int n_in,
                              void* d_out, int out_size, void* d_ws, size_t ws_size,
                              hipStream_t stream) {
  const float* hl  = (const float*)d_in[0];   // [8,1024,768]
  const float* Psi = (const float*)d_in[1];   // [8,1024,64]
  const float* im  = (const float*)d_in[2];   // [8,3,32,32]
  float* out = (float*)d_out;

  const size_t smallBytes = (size_t)MT * DF * 2 + (size_t)MT * KF * 8 + (size_t)MT * 4 +
                            (size_t)MT * 32 * 4 + (size_t)MT * KD * 4 * 4 +
                            (size_t)KD * KD * 4 + 16 * 4096;
  const bool fullS = ws_size >= (size_t)MT * MT * 4 + smallBytes;

  char* ws = (char*)d_ws;
  size_t off = 0;
  auto alloc = [&](size_t bytes) -> void* {
    void* p = ws + off;
    off = (off + bytes + 255) & ~(size_t)255;
    return p;
  };
  float*    S     = (float*)alloc(fullS ? (size_t)MT * MT * 4 : (size_t)RB * MT * 4);
  __bf16*   Xb    = (__bf16*)alloc((size_t)MT * DF * 2);
  int*      fidx  = (int*)alloc((size_t)MT * KF * 4);
  float*    fval  = (float*)alloc((size_t)MT * KF * 4);
  float*    frow  = (float*)alloc((size_t)MT * 4);
  unsigned* pmask = (unsigned*)alloc((size_t)MT * 32 * 4);
  float*    U     = (float*)alloc((size_t)MT * KD * 4);
  float*    V     = (float*)alloc((size_t)MT * KD * 4);
  float*    Wf    = (float*)alloc((size_t)MT * KD * 4);
  float*    W2    = (float*)alloc((size_t)MT * KD * 4);
  float*    Rm    = (float*)alloc((size_t)KD * KD * 4);

  hipMemsetAsync(frow,  0, (size_t)MT * 4, stream);
  hipMemsetAsync(pmask, 0, (size_t)MT * 32 * 4, stream);
  hipMemsetAsync(Rm,    0, (size_t)KD * KD * 4, stream);

  norm_kernel<<<MT, 256, 0, stream>>>(hl, Xb);
  pix_topk_kernel<<<MT / 4, 256, 0, stream>>>(im, pmask);

  if (fullS) {
    gemm_kernel<true><<<2080, 256, 0, stream>>>(Xb, S, 0);
    topk_kernel<<<MT, 256, 0, stream>>>(S, fidx, fval, 0);
  } else {
    for (int rb = 0; rb < MT / RB; ++rb) {
      gemm_kernel<false><<<dim3(MT / 128, RB / 128), 256, 0, stream>>>(Xb, S, rb * RB);
      topk_kernel<<<RB, 256, 0, stream>>>(S, fidx, fval, rb * RB);
    }
  }

  feat_deg_kernel<<<MT / 256, 256, 0, stream>>>(fidx, fval, frow);
  prep_kernel<<<MT, 64, 0, stream>>>(frow, pmask, Psi, U, V);
  gather_feat_kernel<<<MT, 64, 0, stream>>>(fidx, fval, U, Wf);
  gather_pix_kernel<<<MT, 64, 0, stream>>>(pmask, V, W2);
  rmat_kernel<<<dim3(KD, 16), 64, 0, stream>>>(U, Wf, Rm, 1.0f, 1);
  rmat_kernel<<<dim3(KD, 16), 64, 0, stream>>>(V, W2, Rm, PIXW, 0);
  final_kernel<<<1, 256, 0, stream>>>(Rm, out);
}

// Round 5
// 687.571 us; speedup vs baseline: 2.1514x; 1.0427x over previous
//
#include <hip/hip_runtime.h>
#include <hip/hip_bf16.h>
#include <math.h>

// Problem constants (Segmenter_65721589563708)
constexpr int MT  = 8192;   // bs*n
constexpr int DF  = 768;    // feature dim
constexpr int KD  = 64;     // kdim
constexpr int HWP = 1024;   // 32*32 pixels
constexpr int KF  = 32;     // feature kNN
constexpr int KP  = 10;     // pixel kNN
constexpr int RB  = 1024;   // GEMM row-block (fallback path)
#define SQT 3.16227766016837933f   // sqrt(T=10)
#define PIXW 0.05f

typedef __bf16 bf16x8 __attribute__((ext_vector_type(8)));
typedef float  f32x4  __attribute__((ext_vector_type(4)));

// ---------------- 1. normalize rows of X -> bf16 ----------------
__global__ __launch_bounds__(256) void norm_kernel(const float* __restrict__ X,
                                                   __bf16* __restrict__ Xb) {
  __shared__ float red[256];
  const int row = blockIdx.x, tid = threadIdx.x;
  const float* xr = X + (size_t)row * DF;
  float s = 0.f;
  for (int c = tid; c < DF; c += 256) { float v = xr[c]; s += v * v; }
  red[tid] = s; __syncthreads();
  for (int o = 128; o > 0; o >>= 1) { if (tid < o) red[tid] += red[tid + o]; __syncthreads(); }
  const float rn = rsqrtf(red[0]);
  __bf16* hr = Xb + (size_t)row * DF;
  for (int c = tid; c < DF; c += 256) hr[c] = (__bf16)(xr[c] * rn);
}

// ---------------- 2. S = Xb . Xb^T  (bf16 MFMA, XOR-swizzled LDS, m97 staging) ----------
template <bool SYM>
__global__ __launch_bounds__(256) void gemm_kernel(const __bf16* __restrict__ Xb,
                                                   float* __restrict__ S, int rowBase) {
  __shared__ __bf16 As[128 * 64];
  __shared__ __bf16 Bs[128 * 64];
  const int tid = threadIdx.x;
  const int lane = tid & 63;
  const int wv = tid >> 6;
  const int wm = (wv & 1) * 64, wn = (wv >> 1) * 64;
  const int l15 = lane & 15, lq = lane >> 4;
  const int lr8 = lane >> 3, lc8 = lane & 7;   // staging: row-in-group, 16B chunk
  const int rsw = l15 & 7;                     // fragment-row swizzle key

  int m0, n0;
  if (SYM) {
    int L = blockIdx.x, ti = 0;
    while (L >= 64 - ti) { L -= 64 - ti; ++ti; }
    m0 = ti * 128;
    n0 = (ti + L) * 128;
  } else {
    m0 = rowBase + blockIdx.y * 128;
    n0 = blockIdx.x * 128;
  }

  f32x4 acc[4][4];
  #pragma unroll
  for (int i = 0; i < 4; ++i)
    #pragma unroll
    for (int j = 0; j < 4; ++j)
      #pragma unroll
      for (int r = 0; r < 4; ++r) acc[i][j][r] = 0.f;

  for (int kt = 0; kt < 12; ++kt) {
    const int col0 = kt * 64;
    const __bf16* Ag = Xb + (size_t)m0 * DF + col0;
    const __bf16* Bg = Xb + (size_t)n0 * DF + col0;
    #pragma unroll
    for (int i = 0; i < 4; ++i) {
      const int r0 = (wv * 4 + i) * 8;         // 8 rows per issue, wave-uniform base
      const int csw = (lc8 ^ lr8) * 8;
      __builtin_amdgcn_global_load_lds(
          (const __attribute__((address_space(1))) void*)(Ag + (size_t)(r0 + lr8) * DF + csw),
          (__attribute__((address_space(3))) void*)(&As[r0 * 64]), 16, 0, 0);
      __builtin_amdgcn_global_load_lds(
          (const __attribute__((address_space(1))) void*)(Bg + (size_t)(r0 + lr8) * DF + csw),
          (__attribute__((address_space(3))) void*)(&Bs[r0 * 64]), 16, 0, 0);
    }
    __syncthreads();
    #pragma unroll
    for (int kk = 0; kk < 64; kk += 32) {
      bf16x8 af[4], bg[4];
      #pragma unroll
      for (int i = 0; i < 4; ++i)
        af[i] = *(const bf16x8*)(&As[(wm + i * 16 + l15) * 64 + ((((kk >> 3) + lq) ^ rsw) * 8)]);
      #pragma unroll
      for (int j = 0; j < 4; ++j)
        bg[j] = *(const bf16x8*)(&Bs[(wn + j * 16 + l15) * 64 + ((((kk >> 3) + lq) ^ rsw) * 8)]);
      #pragma unroll
      for (int i = 0; i < 4; ++i)
        #pragma unroll
        for (int j = 0; j < 4; ++j)
          acc[i][j] = __builtin_amdgcn_mfma_f32_16x16x32_bf16(af[i], bg[j], acc[i][j], 0, 0, 0);
    }
    __syncthreads();
  }
  #pragma unroll
  for (int i = 0; i < 4; ++i)
    #pragma unroll
    for (int j = 0; j < 4; ++j)
      #pragma unroll
      for (int r = 0; r < 4; ++r) {
        const int lrow = m0 + wm + i * 16 + lq * 4 + r;
        const int col  = n0 + wn + j * 16 + l15;
        const float v = acc[i][j][r];
        if (SYM) {
          S[(size_t)lrow * MT + col] = v;
          S[(size_t)col * MT + lrow] = v;   // mirror; diag tiles: bitwise-identical benign race
        } else {
          S[(size_t)(lrow - rowBase) * MT + col] = v;
        }
      }
}

// ---------------- 3. top-32 per row: single HBM pass, register-resident values ----------------
constexpr int NB   = 1024;   // histogram bins over [0,1]
constexpr int CAND = 2048;   // candidate cap (expected ~33 with random data)
constexpr int VPT  = MT / 256;  // 32 values per thread

__global__ __launch_bounds__(256) void topk_kernel(const float* __restrict__ Sblk,
                                                   int* __restrict__ fidx,
                                                   float* __restrict__ fval, int rowBase) {
  __shared__ int   hist[NB];
  __shared__ int   chunk[256];
  __shared__ float cval[CAND];
  __shared__ int   cidx[CAND];
  __shared__ int   cnt, tbin;
  const int tid = threadIdx.x;
  const int rl = blockIdx.x;
  const int grow = rowBase + rl;
  const float* srow = Sblk + (size_t)rl * MT;
  float vals[VPT];
  #pragma unroll
  for (int i = tid; i < NB; i += 256) hist[i] = 0;
  if (tid == 0) cnt = 0;
  __syncthreads();
  #pragma unroll
  for (int i = 0; i < VPT; ++i) {
    const int c = tid + i * 256;
    float v = srow[c];
    if (c == grow) v = -1.f;
    vals[i] = v;
    if (v > 0.f) {
      int b = (int)fminf(v * (float)NB, (float)(NB - 1));
      atomicAdd(&hist[b], 1);
    }
  }
  __syncthreads();
  { int s = 0;
    #pragma unroll
    for (int i = 0; i < 4; ++i) s += hist[tid * 4 + i];
    chunk[tid] = s; }
  __syncthreads();
  if (tid == 0) {
    int acc = 0, ch = 255;
    for (; ch > 0; --ch) {
      if (acc + chunk[ch] >= KF) break;
      acc += chunk[ch];
    }
    int b = ch * 4 + 3;
    for (; b > ch * 4; --b) {
      if (acc + hist[b] >= KF) break;
      acc += hist[b];
    }
    tbin = b;
  }
  __syncthreads();
  const float thr = (float)tbin * (1.f / (float)NB);
  #pragma unroll
  for (int i = 0; i < VPT; ++i) {
    float v = vals[i];
    if (v > 0.f && v >= thr) {
      int pos = atomicAdd(&cnt, 1);
      if (pos < CAND) { cval[pos] = v; cidx[pos] = tid + i * 256; }
    }
  }
  __syncthreads();
  const int n = min(cnt, CAND);
  if (tid < 64) {
    for (int it = 0; it < KF; ++it) {
      float bm = -1.f; int bp = -1;
      for (int e = tid; e < n; e += 64)
        if (cval[e] > bm) { bm = cval[e]; bp = e; }
      #pragma unroll
      for (int o = 32; o > 0; o >>= 1) {
        float ov = __shfl_down(bm, o);
        int   op = __shfl_down(bp, o);
        if (ov > bm) { bm = ov; bp = op; }
      }
      bm = __shfl(bm, 0); bp = __shfl(bp, 0);
      if (tid == 0) {
        if (bp >= 0) {
          fval[(size_t)grow * KF + it] = bm;
          fidx[(size_t)grow * KF + it] = cidx[bp];
          cval[bp] = -2.f;
        } else {
          fval[(size_t)grow * KF + it] = 0.f;
          fidx[(size_t)grow * KF + it] = grow;
        }
      }
    }
  }
}

// ---------------- 4. pixel kNN: one wave per pixel, register-resident distances ----------------
__global__ __launch_bounds__(256) void pix_topk_kernel(const float* __restrict__ im,
                                                       unsigned* __restrict__ pmask) {
  __shared__ float fr[HWP], fg[HWP], fb[HWP];
  const int tid = threadIdx.x;
  const int lane = tid & 63, wv = tid >> 6;
  const int b = blockIdx.x >> 8;
  const int p = ((blockIdx.x & 255) << 2) + wv;
  const float* imb = im + (size_t)b * 3 * HWP;
  for (int q = tid; q < HWP; q += 256) {
    fr[q] = imb[q]; fg[q] = imb[HWP + q]; fb[q] = imb[2 * HWP + q];
  }
  __syncthreads();
  const float pr = fr[p], pg = fg[p], pb = fb[p];
  const float px = (float)(p & 31) * (1.f / 31.f), py = (float)(p >> 5) * (1.f / 31.f);
  float d0[16], d1[16];
  #pragma unroll
  for (int i = 0; i < 16; ++i) {
    const int q = lane + (i << 6);
    float dr = (fr[q] - pr) * 0.5f, dg = (fg[q] - pg) * 0.5f, db = (fb[q] - pb) * 0.5f;
    float drgb = dr * dr + dg * dg + db * db;
    float dx = (float)(q & 31) * (1.f / 31.f) - px;
    float dy = (float)(q >> 5) * (1.f / 31.f) - py;
    float cd = dx * dx + dy * dy;
    d0[i] = (q == p) ? 1e30f : drgb + 4.00f * cd;   // dw = 2.0
    d1[i] = (q == p) ? 1e30f : drgb + 0.01f * cd;   // dw = 0.1
  }
  const int mrow = (b << 10) + p;
  auto doPass = [&](float (&dd)[16]) {
    for (int it = 0; it < KP; ++it) {
      float bm = 1e30f; int bq = 0;
      #pragma unroll
      for (int i = 0; i < 16; ++i) {
        const int q = lane + (i << 6);
        if (dd[i] < bm) { bm = dd[i]; bq = q; }
      }
      #pragma unroll
      for (int o = 32; o > 0; o >>= 1) {
        float ov = __shfl_down(bm, o);
        int   oq = __shfl_down(bq, o);
        if (ov < bm) { bm = ov; bq = oq; }
      }
      bq = __shfl(bq, 0);
      if (lane == 0) {
        atomicOr(&pmask[(size_t)mrow * 32 + (bq >> 5)], 1u << (bq & 31));
        atomicOr(&pmask[((size_t)((b << 10) + bq)) * 32 + (p >> 5)], 1u << (p & 31));
      }
      #pragma unroll
      for (int i = 0; i < 16; ++i)
        if (lane + (i << 6) == bq) dd[i] = 1e30f;
    }
  };
  doPass(d0);
  doPass(d1);
}

// ---------------- 5. feature degrees (row sums of (res+res^T)/2) ----------------
__global__ void feat_deg_kernel(const int* __restrict__ fidx, const float* __restrict__ fval,
                                float* __restrict__ frow) {
  int m = blockIdx.x * blockDim.x + threadIdx.x;
  if (m >= MT) return;
  float s = 0.f;
  for (int k = 0; k < KF; ++k) {
    float v = fval[m * KF + k];
    s += v;
    atomicAdd(&frow[fidx[m * KF + k]], 0.5f * v);
  }
  atomicAdd(&frow[m], 0.5f * s);
}

// ---------------- 6. prep: U = dfeat*sqrt(T)*Psi, V = d2r*sqrt(T)*Psi ----------------
__global__ __launch_bounds__(64) void prep_kernel(const float* __restrict__ frow,
                                                  const unsigned* __restrict__ pmask,
                                                  const float* __restrict__ Psi,
                                                  float* __restrict__ U,
                                                  float* __restrict__ V) {
  const int m = blockIdx.x, t = threadIdx.x;
  int pd = (t < 32) ? __popc(pmask[(size_t)m * 32 + t]) : 0;
  #pragma unroll
  for (int o = 16; o > 0; o >>= 1) pd += __shfl_down(pd, o);
  pd = __shfl(pd, 0);
  const float fr = frow[m];
  const float df = (fr > 0.f) ? rsqrtf(fr) : 0.f;
  const float dp = (pd > 0) ? rsqrtf((float)pd) : 0.f;
  const float p = Psi[(size_t)m * KD + t] * SQT;
  U[(size_t)m * KD + t] = df * p;
  V[(size_t)m * KD + t] = dp * p;
}

// ---------------- 7. Wf[j] = sum_k 0.5*v_jk * U[c_jk]   (pure gather, no atomics) ---------
__global__ __launch_bounds__(64) void gather_feat_kernel(const int* __restrict__ fidx,
                                                         const float* __restrict__ fval,
                                                         const float* __restrict__ U,
                                                         float* __restrict__ Wf) {
  const int j = blockIdx.x, t = threadIdx.x;
  float acc = 0.f;
  for (int k = 0; k < KF; ++k) {
    float v = fval[j * KF + k];
    int   c = fidx[j * KF + k];
    acc += 0.5f * v * U[(size_t)c * KD + t];
  }
  Wf[(size_t)j * KD + t] = acc;
}

// ---------------- 8. W2[m] = sum_{q in adj(m)} V[q]   (pure gather) ----------------
__global__ __launch_bounds__(64) void gather_pix_kernel(const unsigned* __restrict__ pmask,
                                                        const float* __restrict__ V,
                                                        float* __restrict__ W2) {
  __shared__ int list[HWP];
  __shared__ int cnt;
  const int m = blockIdx.x;
  const int t = threadIdx.x;
  const int b = m >> 10;
  if (t == 0) cnt = 0;
  __syncthreads();
  if (t < 32) {
    unsigned bits = pmask[(size_t)m * 32 + t];
    while (bits) {
      int bit = __ffs(bits) - 1;
      bits &= bits - 1;
      int pos = atomicAdd(&cnt, 1);
      list[pos] = t * 32 + bit;
    }
  }
  __syncthreads();
  const int n = cnt;
  float acc = 0.f;
  for (int e = 0; e < n; ++e)
    acc += V[(size_t)(b * HWP + list[e]) * KD + t];
  W2[(size_t)m * KD + t] = acc;
}

// ---------------- 9. fused R = (U^T Wf) + (U^T Wf)^T + PIXW * (V^T W2) ----------------
// 64 blocks x 128 rows; 8-row LDS tiles; thread (g=tid>>6, c=tid&63) owns a=g*16+i.
__global__ __launch_bounds__(256) void rmat_fused_kernel(const float* __restrict__ U,
                                                         const float* __restrict__ Wf,
                                                         const float* __restrict__ V,
                                                         const float* __restrict__ W2,
                                                         float* __restrict__ Rm) {
  __shared__ float sU[8][KD], sWf[8][KD], sV[8][KD], sW2[8][KD];
  const int tid = threadIdx.x;
  const int c = tid & 63, g = tid >> 6;
  float accf[16], accp[16];
  #pragma unroll
  for (int i = 0; i < 16; ++i) { accf[i] = 0.f; accp[i] = 0.f; }
  const int rowBeg = blockIdx.x * 128;
  for (int r0 = rowBeg; r0 < rowBeg + 128; r0 += 8) {
    #pragma unroll
    for (int e = tid; e < 8 * KD; e += 256) {
      const int r = e >> 6, cc = e & 63;
      const size_t gi = (size_t)(r0 + r) * KD + cc;
      sU[r][cc]  = U[gi];
      sWf[r][cc] = Wf[gi];
      sV[r][cc]  = V[gi];
      sW2[r][cc] = W2[gi];
    }
    __syncthreads();
    #pragma unroll
    for (int r = 0; r < 8; ++r) {
      const float wf = sWf[r][c], w2 = sW2[r][c];
      const f32x4* u4 = (const f32x4*)&sU[r][g * 16];
      const f32x4* v4 = (const f32x4*)&sV[r][g * 16];
      #pragma unroll
      for (int q = 0; q < 4; ++q) {
        const f32x4 uu = u4[q], vv = v4[q];
        #pragma unroll
        for (int k = 0; k < 4; ++k) {
          accf[q * 4 + k] += uu[k] * wf;
          accp[q * 4 + k] += vv[k] * w2;
        }
      }
    }
    __syncthreads();
  }
  #pragma unroll
  for (int i = 0; i < 16; ++i) {
    const int a = g * 16 + i;
    atomicAdd(&Rm[a * KD + c], accf[i] + PIXW * accp[i]);
    atomicAdd(&Rm[c * KD + a], accf[i]);
  }
}

// ---------------- 10. loss = -tr(R)/kd ; reg = sum(triu(R^2,1))/kd ----------------
__global__ __launch_bounds__(256) void final_kernel(const float* __restrict__ Rm,
                                                    float* __restrict__ out) {
  __shared__ float redt[256], redr[256];
  const int tid = threadIdx.x;
  float tr = 0.f, rg = 0.f;
  for (int e = tid; e < KD * KD; e += 256) {
    int a = e >> 6, c = e & 63;
    float v = Rm[e];
    if (a == c) tr += v;
    else if (c > a) rg += v * v;
  }
  redt[tid] = tr; redr[tid] = rg;
  __syncthreads();
  for (int o = 128; o > 0; o >>= 1) {
    if (tid < o) { redt[tid] += redt[tid + o]; redr[tid] += redr[tid + o]; }
    __syncthreads();
  }
  if (tid == 0) {
    out[0] = -redt[0] / (float)KD;
    out[1] = redr[0] / (float)KD;
  }
}

extern "C" void kernel_launch(void* const* d_in, const int* in_sizes, int n_in,
                              void* d_out, int out_size, void* d_ws, size_t ws_size,
                              hipStream_t stream) {
  const float* hl  = (const float*)d_in[0];   // [8,1024,768]
  const float* Psi = (const float*)d_in[1];   // [8,1024,64]
  const float* im  = (const float*)d_in[2];   // [8,3,32,32]
  float* out = (float*)d_out;

  const size_t smallBytes = (size_t)MT * DF * 2 + (size_t)MT * KF * 8 + (size_t)MT * 4 +
                            (size_t)MT * 32 * 4 + (size_t)MT * KD * 4 * 4 +
                            (size_t)KD * KD * 4 + 16 * 4096;
  const bool fullS = ws_size >= (size_t)MT * MT * 4 + smallBytes;

  char* ws = (char*)d_ws;
  size_t off = 0;
  auto alloc = [&](size_t bytes) -> void* {
    void* p = ws + off;
    off = (off + bytes + 255) & ~(size_t)255;
    return p;
  };
  float*    S     = (float*)alloc(fullS ? (size_t)MT * MT * 4 : (size_t)RB * MT * 4);
  __bf16*   Xb    = (__bf16*)alloc((size_t)MT * DF * 2);
  int*      fidx  = (int*)alloc((size_t)MT * KF * 4);
  float*    fval  = (float*)alloc((size_t)MT * KF * 4);
  float*    frow  = (float*)alloc((size_t)MT * 4);
  unsigned* pmask = (unsigned*)alloc((size_t)MT * 32 * 4);
  float*    U     = (float*)alloc((size_t)MT * KD * 4);
  float*    V     = (float*)alloc((size_t)MT * KD * 4);
  float*    Wf    = (float*)alloc((size_t)MT * KD * 4);
  float*    W2    = (float*)alloc((size_t)MT * KD * 4);
  float*    Rm    = (float*)alloc((size_t)KD * KD * 4);

  hipMemsetAsync(frow,  0, (size_t)MT * 4, stream);
  hipMemsetAsync(pmask, 0, (size_t)MT * 32 * 4, stream);
  hipMemsetAsync(Rm,    0, (size_t)KD * KD * 4, stream);

  norm_kernel<<<MT, 256, 0, stream>>>(hl, Xb);
  pix_topk_kernel<<<MT / 4, 256, 0, stream>>>(im, pmask);

  if (fullS) {
    gemm_kernel<true><<<2080, 256, 0, stream>>>(Xb, S, 0);
    topk_kernel<<<MT, 256, 0, stream>>>(S, fidx, fval, 0);
  } else {
    for (int rb = 0; rb < MT / RB; ++rb) {
      gemm_kernel<false><<<dim3(MT / 128, RB / 128), 256, 0, stream>>>(Xb, S, rb * RB);
      topk_kernel<<<RB, 256, 0, stream>>>(S, fidx, fval, rb * RB);
    }
  }

  feat_deg_kernel<<<MT / 256, 256, 0, stream>>>(fidx, fval, frow);
  prep_kernel<<<MT, 64, 0, stream>>>(frow, pmask, Psi, U, V);
  gather_feat_kernel<<<MT, 64, 0, stream>>>(fidx, fval, U, Wf);
  gather_pix_kernel<<<MT, 64, 0, stream>>>(pmask, V, W2);
  rmat_fused_kernel<<<64, 256, 0, stream>>>(U, Wf, V, W2, Rm);
  final_kernel<<<1, 256, 0, stream>>>(Rm, out);
}

// Round 6
// 574.368 us; speedup vs baseline: 2.5755x; 1.1971x over previous
//
#include <hip/hip_runtime.h>
#include <hip/hip_bf16.h>
#include <math.h>

// Problem constants (Segmenter_65721589563708)
constexpr int MT  = 8192;   // bs*n
constexpr int DF  = 768;    // feature dim
constexpr int KD  = 64;     // kdim
constexpr int HWP = 1024;   // 32*32 pixels
constexpr int KF  = 32;     // feature kNN
constexpr int KP  = 10;     // pixel kNN
constexpr int RB  = 1024;   // GEMM row-block (fallback path)
constexpr int RPB = 256;    // rmat partial blocks
#define SQT 3.16227766016837933f   // sqrt(T=10)
#define PIXW 0.05f

typedef __bf16 bf16x8 __attribute__((ext_vector_type(8)));
typedef float  f32x4  __attribute__((ext_vector_type(4)));
typedef _Float16 f16;

// ---------------- 1. normalize rows of X -> bf16 ----------------
__global__ __launch_bounds__(256) void norm_kernel(const float* __restrict__ X,
                                                   __bf16* __restrict__ Xb) {
  __shared__ float red[256];
  const int row = blockIdx.x, tid = threadIdx.x;
  const float* xr = X + (size_t)row * DF;
  float s = 0.f;
  for (int c = tid; c < DF; c += 256) { float v = xr[c]; s += v * v; }
  red[tid] = s; __syncthreads();
  for (int o = 128; o > 0; o >>= 1) { if (tid < o) red[tid] += red[tid + o]; __syncthreads(); }
  const float rn = rsqrtf(red[0]);
  __bf16* hr = Xb + (size_t)row * DF;
  for (int c = tid; c < DF; c += 256) hr[c] = (__bf16)(xr[c] * rn);
}

// ---------------- 2. S = Xb . Xb^T  (bf16 MFMA -> fp16 S, XOR-swizzled LDS) ----------
template <bool SYM>
__global__ __launch_bounds__(256) void gemm_kernel(const __bf16* __restrict__ Xb,
                                                   f16* __restrict__ S, int rowBase) {
  __shared__ __bf16 As[128 * 64];
  __shared__ __bf16 Bs[128 * 64];
  const int tid = threadIdx.x;
  const int lane = tid & 63;
  const int wv = tid >> 6;
  const int wm = (wv & 1) * 64, wn = (wv >> 1) * 64;
  const int l15 = lane & 15, lq = lane >> 4;
  const int lr8 = lane >> 3, lc8 = lane & 7;   // staging: row-in-group, 16B chunk
  const int rsw = l15 & 7;                     // fragment-row swizzle key

  int m0, n0;
  if (SYM) {
    int L = blockIdx.x, ti = 0;
    while (L >= 64 - ti) { L -= 64 - ti; ++ti; }
    m0 = ti * 128;
    n0 = (ti + L) * 128;
  } else {
    m0 = rowBase + blockIdx.y * 128;
    n0 = blockIdx.x * 128;
  }

  f32x4 acc[4][4];
  #pragma unroll
  for (int i = 0; i < 4; ++i)
    #pragma unroll
    for (int j = 0; j < 4; ++j)
      #pragma unroll
      for (int r = 0; r < 4; ++r) acc[i][j][r] = 0.f;

  for (int kt = 0; kt < 12; ++kt) {
    const int col0 = kt * 64;
    const __bf16* Ag = Xb + (size_t)m0 * DF + col0;
    const __bf16* Bg = Xb + (size_t)n0 * DF + col0;
    #pragma unroll
    for (int i = 0; i < 4; ++i) {
      const int r0 = (wv * 4 + i) * 8;         // 8 rows per issue, wave-uniform base
      const int csw = (lc8 ^ lr8) * 8;
      __builtin_amdgcn_global_load_lds(
          (const __attribute__((address_space(1))) void*)(Ag + (size_t)(r0 + lr8) * DF + csw),
          (__attribute__((address_space(3))) void*)(&As[r0 * 64]), 16, 0, 0);
      __builtin_amdgcn_global_load_lds(
          (const __attribute__((address_space(1))) void*)(Bg + (size_t)(r0 + lr8) * DF + csw),
          (__attribute__((address_space(3))) void*)(&Bs[r0 * 64]), 16, 0, 0);
    }
    __syncthreads();
    #pragma unroll
    for (int kk = 0; kk < 64; kk += 32) {
      bf16x8 af[4], bg[4];
      #pragma unroll
      for (int i = 0; i < 4; ++i)
        af[i] = *(const bf16x8*)(&As[(wm + i * 16 + l15) * 64 + ((((kk >> 3) + lq) ^ rsw) * 8)]);
      #pragma unroll
      for (int j = 0; j < 4; ++j)
        bg[j] = *(const bf16x8*)(&Bs[(wn + j * 16 + l15) * 64 + ((((kk >> 3) + lq) ^ rsw) * 8)]);
      #pragma unroll
      for (int i = 0; i < 4; ++i)
        #pragma unroll
        for (int j = 0; j < 4; ++j)
          acc[i][j] = __builtin_amdgcn_mfma_f32_16x16x32_bf16(af[i], bg[j], acc[i][j], 0, 0, 0);
    }
    __syncthreads();
  }
  #pragma unroll
  for (int i = 0; i < 4; ++i)
    #pragma unroll
    for (int j = 0; j < 4; ++j)
      #pragma unroll
      for (int r = 0; r < 4; ++r) {
        const int lrow = m0 + wm + i * 16 + lq * 4 + r;
        const int col  = n0 + wn + j * 16 + l15;
        const f16 v = (f16)acc[i][j][r];
        if (SYM) {
          S[(size_t)lrow * MT + col] = v;
          S[(size_t)col * MT + lrow] = v;   // mirror; diag tiles: bitwise-identical benign race
        } else {
          S[(size_t)(lrow - rowBase) * MT + col] = v;
        }
      }
}

// ---------------- 3. top-32 per row: single HBM pass, register-resident values ----------------
constexpr int NB   = 1024;   // histogram bins over [0,1]
constexpr int CAND = 2048;   // candidate cap (expected ~33 with random data)
constexpr int VPT  = MT / 256;  // 32 values per thread

__global__ __launch_bounds__(256) void topk_kernel(const f16* __restrict__ Sblk,
                                                   int* __restrict__ fidx,
                                                   float* __restrict__ fval, int rowBase) {
  __shared__ int   hist[NB];
  __shared__ int   chunk[256];
  __shared__ float cval[CAND];
  __shared__ int   cidx[CAND];
  __shared__ int   cnt, tbin;
  const int tid = threadIdx.x;
  const int rl = blockIdx.x;
  const int grow = rowBase + rl;
  const f16* srow = Sblk + (size_t)rl * MT;
  float vals[VPT];
  #pragma unroll
  for (int i = tid; i < NB; i += 256) hist[i] = 0;
  if (tid == 0) cnt = 0;
  __syncthreads();
  #pragma unroll
  for (int i = 0; i < VPT; ++i) {
    const int c = tid + i * 256;
    float v = (float)srow[c];
    if (c == grow) v = -1.f;
    vals[i] = v;
    if (v > 0.f) {
      int b = (int)fminf(v * (float)NB, (float)(NB - 1));
      atomicAdd(&hist[b], 1);
    }
  }
  __syncthreads();
  { int s = 0;
    #pragma unroll
    for (int i = 0; i < 4; ++i) s += hist[tid * 4 + i];
    chunk[tid] = s; }
  __syncthreads();
  if (tid == 0) {
    int acc = 0, ch = 255;
    for (; ch > 0; --ch) {
      if (acc + chunk[ch] >= KF) break;
      acc += chunk[ch];
    }
    int b = ch * 4 + 3;
    for (; b > ch * 4; --b) {
      if (acc + hist[b] >= KF) break;
      acc += hist[b];
    }
    tbin = b;
  }
  __syncthreads();
  const float thr = (float)tbin * (1.f / (float)NB);
  #pragma unroll
  for (int i = 0; i < VPT; ++i) {
    float v = vals[i];
    if (v > 0.f && v >= thr) {
      int pos = atomicAdd(&cnt, 1);
      if (pos < CAND) { cval[pos] = v; cidx[pos] = tid + i * 256; }
    }
  }
  __syncthreads();
  const int n = min(cnt, CAND);
  if (tid < 64) {
    for (int it = 0; it < KF; ++it) {
      float bm = -1.f; int bp = -1;
      for (int e = tid; e < n; e += 64)
        if (cval[e] > bm) { bm = cval[e]; bp = e; }
      #pragma unroll
      for (int o = 32; o > 0; o >>= 1) {
        float ov = __shfl_down(bm, o);
        int   op = __shfl_down(bp, o);
        if (ov > bm) { bm = ov; bp = op; }
      }
      bm = __shfl(bm, 0); bp = __shfl(bp, 0);
      if (tid == 0) {
        if (bp >= 0) {
          fval[(size_t)grow * KF + it] = bm;
          fidx[(size_t)grow * KF + it] = cidx[bp];
          cval[bp] = -2.f;
        } else {
          fval[(size_t)grow * KF + it] = 0.f;
          fidx[(size_t)grow * KF + it] = grow;
        }
      }
    }
  }
}

// ---------------- 4. pixel kNN: one wave per pixel, register-resident distances ----------------
__global__ __launch_bounds__(256) void pix_topk_kernel(const float* __restrict__ im,
                                                       unsigned* __restrict__ pmask) {
  __shared__ float fr[HWP], fg[HWP], fb[HWP];
  const int tid = threadIdx.x;
  const int lane = tid & 63, wv = tid >> 6;
  const int b = blockIdx.x >> 8;
  const int p = ((blockIdx.x & 255) << 2) + wv;
  const float* imb = im + (size_t)b * 3 * HWP;
  for (int q = tid; q < HWP; q += 256) {
    fr[q] = imb[q]; fg[q] = imb[HWP + q]; fb[q] = imb[2 * HWP + q];
  }
  __syncthreads();
  const float pr = fr[p], pg = fg[p], pb = fb[p];
  const float px = (float)(p & 31) * (1.f / 31.f), py = (float)(p >> 5) * (1.f / 31.f);
  float d0[16], d1[16];
  #pragma unroll
  for (int i = 0; i < 16; ++i) {
    const int q = lane + (i << 6);
    float dr = (fr[q] - pr) * 0.5f, dg = (fg[q] - pg) * 0.5f, db = (fb[q] - pb) * 0.5f;
    float drgb = dr * dr + dg * dg + db * db;
    float dx = (float)(q & 31) * (1.f / 31.f) - px;
    float dy = (float)(q >> 5) * (1.f / 31.f) - py;
    float cd = dx * dx + dy * dy;
    d0[i] = (q == p) ? 1e30f : drgb + 4.00f * cd;   // dw = 2.0
    d1[i] = (q == p) ? 1e30f : drgb + 0.01f * cd;   // dw = 0.1
  }
  const int mrow = (b << 10) + p;
  auto doPass = [&](float (&dd)[16]) {
    for (int it = 0; it < KP; ++it) {
      float bm = 1e30f; int bq = 0;
      #pragma unroll
      for (int i = 0; i < 16; ++i) {
        const int q = lane + (i << 6);
        if (dd[i] < bm) { bm = dd[i]; bq = q; }
      }
      #pragma unroll
      for (int o = 32; o > 0; o >>= 1) {
        float ov = __shfl_down(bm, o);
        int   oq = __shfl_down(bq, o);
        if (ov < bm) { bm = ov; bq = oq; }
      }
      bq = __shfl(bq, 0);
      if (lane == 0) {
        atomicOr(&pmask[(size_t)mrow * 32 + (bq >> 5)], 1u << (bq & 31));
        atomicOr(&pmask[((size_t)((b << 10) + bq)) * 32 + (p >> 5)], 1u << (p & 31));
      }
      #pragma unroll
      for (int i = 0; i < 16; ++i)
        if (lane + (i << 6) == bq) dd[i] = 1e30f;
    }
  };
  doPass(d0);
  doPass(d1);
}

// ---------------- 5. feature degrees (row sums of (res+res^T)/2) ----------------
__global__ void feat_deg_kernel(const int* __restrict__ fidx, const float* __restrict__ fval,
                                float* __restrict__ frow) {
  int m = blockIdx.x * blockDim.x + threadIdx.x;
  if (m >= MT) return;
  float s = 0.f;
  for (int k = 0; k < KF; ++k) {
    float v = fval[m * KF + k];
    s += v;
    atomicAdd(&frow[fidx[m * KF + k]], 0.5f * v);
  }
  atomicAdd(&frow[m], 0.5f * s);
}

// ---------------- 6. prep: U = dfeat*sqrt(T)*Psi, V = d2r*sqrt(T)*Psi ----------------
__global__ __launch_bounds__(64) void prep_kernel(const float* __restrict__ frow,
                                                  const unsigned* __restrict__ pmask,
                                                  const float* __restrict__ Psi,
                                                  float* __restrict__ U,
                                                  float* __restrict__ V) {
  const int m = blockIdx.x, t = threadIdx.x;
  int pd = (t < 32) ? __popc(pmask[(size_t)m * 32 + t]) : 0;
  #pragma unroll
  for (int o = 16; o > 0; o >>= 1) pd += __shfl_down(pd, o);
  pd = __shfl(pd, 0);
  const float fr = frow[m];
  const float df = (fr > 0.f) ? rsqrtf(fr) : 0.f;
  const float dp = (pd > 0) ? rsqrtf((float)pd) : 0.f;
  const float p = Psi[(size_t)m * KD + t] * SQT;
  U[(size_t)m * KD + t] = df * p;
  V[(size_t)m * KD + t] = dp * p;
}

// ---------------- 7. Wf[j] = sum_k 0.5*v_jk * U[c_jk]   (pure gather, no atomics) ---------
__global__ __launch_bounds__(64) void gather_feat_kernel(const int* __restrict__ fidx,
                                                         const float* __restrict__ fval,
                                                         const float* __restrict__ U,
                                                         float* __restrict__ Wf) {
  const int j = blockIdx.x, t = threadIdx.x;
  float acc = 0.f;
  for (int k = 0; k < KF; ++k) {
    float v = fval[j * KF + k];
    int   c = fidx[j * KF + k];
    acc += 0.5f * v * U[(size_t)c * KD + t];
  }
  Wf[(size_t)j * KD + t] = acc;
}

// ---------------- 8. W2[m] = sum_{q in adj(m)} V[q]   (pure gather) ----------------
__global__ __launch_bounds__(64) void gather_pix_kernel(const unsigned* __restrict__ pmask,
                                                        const float* __restrict__ V,
                                                        float* __restrict__ W2) {
  __shared__ int list[HWP];
  __shared__ int cnt;
  const int m = blockIdx.x;
  const int t = threadIdx.x;
  const int b = m >> 10;
  if (t == 0) cnt = 0;
  __syncthreads();
  if (t < 32) {
    unsigned bits = pmask[(size_t)m * 32 + t];
    while (bits) {
      int bit = __ffs(bits) - 1;
      bits &= bits - 1;
      int pos = atomicAdd(&cnt, 1);
      list[pos] = t * 32 + bit;
    }
  }
  __syncthreads();
  const int n = cnt;
  float acc = 0.f;
  for (int e = 0; e < n; ++e)
    acc += V[(size_t)(b * HWP + list[e]) * KD + t];
  W2[(size_t)m * KD + t] = acc;
}

// ---------------- 9a. partial products: Pf[b] = U[rows]^T Wf[rows], Pp likewise -----------
// 256 blocks x 32 rows; no atomics, full-chip parallel.
__global__ __launch_bounds__(256) void rmat_part_kernel(const float* __restrict__ U,
                                                        const float* __restrict__ Wf,
                                                        const float* __restrict__ V,
                                                        const float* __restrict__ W2,
                                                        float* __restrict__ Pf,
                                                        float* __restrict__ Pp) {
  __shared__ float sU[8][KD], sWf[8][KD], sV[8][KD], sW2[8][KD];
  const int tid = threadIdx.x;
  const int c = tid & 63, g = tid >> 6;
  float accf[16], accp[16];
  #pragma unroll
  for (int i = 0; i < 16; ++i) { accf[i] = 0.f; accp[i] = 0.f; }
  const int rowBeg = blockIdx.x * (MT / RPB);
  for (int r0 = rowBeg; r0 < rowBeg + MT / RPB; r0 += 8) {
    #pragma unroll
    for (int e = tid; e < 8 * KD; e += 256) {
      const int r = e >> 6, cc = e & 63;
      const size_t gi = (size_t)(r0 + r) * KD + cc;
      sU[r][cc]  = U[gi];
      sWf[r][cc] = Wf[gi];
      sV[r][cc]  = V[gi];
      sW2[r][cc] = W2[gi];
    }
    __syncthreads();
    #pragma unroll
    for (int r = 0; r < 8; ++r) {
      const float wf = sWf[r][c], w2 = sW2[r][c];
      const f32x4* u4 = (const f32x4*)&sU[r][g * 16];
      const f32x4* v4 = (const f32x4*)&sV[r][g * 16];
      #pragma unroll
      for (int q = 0; q < 4; ++q) {
        const f32x4 uu = u4[q], vv = v4[q];
        #pragma unroll
        for (int k = 0; k < 4; ++k) {
          accf[q * 4 + k] += uu[k] * wf;
          accp[q * 4 + k] += vv[k] * w2;
        }
      }
    }
    __syncthreads();
  }
  float* pf = Pf + (size_t)blockIdx.x * KD * KD;
  float* pp = Pp + (size_t)blockIdx.x * KD * KD;
  #pragma unroll
  for (int i = 0; i < 16; ++i) {
    const int a = g * 16 + i;
    pf[a * KD + c] = accf[i];
    pp[a * KD + c] = accp[i];
  }
}

// ---------------- 9b. Rm = sum_b (Pf[b] + Pf[b]^T + PIXW*Pp[b]) ----------------
__global__ __launch_bounds__(256) void rmat_reduce_kernel(const float* __restrict__ Pf,
                                                          const float* __restrict__ Pp,
                                                          float* __restrict__ Rm) {
  const int e = blockIdx.x * 256 + threadIdx.x;   // 16 blocks
  const int a = e >> 6, c = e & 63;
  const int eT = c * KD + a;
  float f = 0.f, ft = 0.f, p = 0.f;
  #pragma unroll 8
  for (int b = 0; b < RPB; ++b) {
    f  += Pf[(size_t)b * KD * KD + e];
    ft += Pf[(size_t)b * KD * KD + eT];
    p  += Pp[(size_t)b * KD * KD + e];
  }
  Rm[e] = f + ft + PIXW * p;
}

// ---------------- 10. loss = -tr(R)/kd ; reg = sum(triu(R^2,1))/kd ----------------
__global__ __launch_bounds__(256) void final_kernel(const float* __restrict__ Rm,
                                                    float* __restrict__ out) {
  __shared__ float redt[256], redr[256];
  const int tid = threadIdx.x;
  float tr = 0.f, rg = 0.f;
  for (int e = tid; e < KD * KD; e += 256) {
    int a = e >> 6, c = e & 63;
    float v = Rm[e];
    if (a == c) tr += v;
    else if (c > a) rg += v * v;
  }
  redt[tid] = tr; redr[tid] = rg;
  __syncthreads();
  for (int o = 128; o > 0; o >>= 1) {
    if (tid < o) { redt[tid] += redt[tid + o]; redr[tid] += redr[tid + o]; }
    __syncthreads();
  }
  if (tid == 0) {
    out[0] = -redt[0] / (float)KD;
    out[1] = redr[0] / (float)KD;
  }
}

extern "C" void kernel_launch(void* const* d_in, const int* in_sizes, int n_in,
                              void* d_out, int out_size, void* d_ws, size_t ws_size,
                              hipStream_t stream) {
  const float* hl  = (const float*)d_in[0];   // [8,1024,768]
  const float* Psi = (const float*)d_in[1];   // [8,1024,64]
  const float* im  = (const float*)d_in[2];   // [8,3,32,32]
  float* out = (float*)d_out;

  const size_t smallBytes = (size_t)MT * DF * 2 + (size_t)MT * KF * 8 + (size_t)MT * 4 +
                            (size_t)MT * 32 * 4 + (size_t)MT * KD * 4 * 4 +
                            (size_t)RPB * KD * KD * 4 * 2 + (size_t)KD * KD * 4 + 32 * 4096;
  const bool fullS = ws_size >= (size_t)MT * MT * 2 + smallBytes;

  char* ws = (char*)d_ws;
  size_t off = 0;
  auto alloc = [&](size_t bytes) -> void* {
    void* p = ws + off;
    off = (off + bytes + 255) & ~(size_t)255;
    return p;
  };
  f16*      S     = (f16*)alloc(fullS ? (size_t)MT * MT * 2 : (size_t)RB * MT * 2);
  __bf16*   Xb    = (__bf16*)alloc((size_t)MT * DF * 2);
  int*      fidx  = (int*)alloc((size_t)MT * KF * 4);
  float*    fval  = (float*)alloc((size_t)MT * KF * 4);
  float*    frow  = (float*)alloc((size_t)MT * 4);
  unsigned* pmask = (unsigned*)alloc((size_t)MT * 32 * 4);
  float*    U     = (float*)alloc((size_t)MT * KD * 4);
  float*    V     = (float*)alloc((size_t)MT * KD * 4);
  float*    Wf    = (float*)alloc((size_t)MT * KD * 4);
  float*    W2    = (float*)alloc((size_t)MT * KD * 4);
  float*    Pf    = (float*)alloc((size_t)RPB * KD * KD * 4);
  float*    Pp    = (float*)alloc((size_t)RPB * KD * KD * 4);
  float*    Rm    = (float*)alloc((size_t)KD * KD * 4);

  hipMemsetAsync(frow,  0, (size_t)MT * 4, stream);
  hipMemsetAsync(pmask, 0, (size_t)MT * 32 * 4, stream);

  norm_kernel<<<MT, 256, 0, stream>>>(hl, Xb);
  pix_topk_kernel<<<MT / 4, 256, 0, stream>>>(im, pmask);

  if (fullS) {
    gemm_kernel<true><<<2080, 256, 0, stream>>>(Xb, S, 0);
    topk_kernel<<<MT, 256, 0, stream>>>(S, fidx, fval, 0);
  } else {
    for (int rb = 0; rb < MT / RB; ++rb) {
      gemm_kernel<false><<<dim3(MT / 128, RB / 128), 256, 0, stream>>>(Xb, S, rb * RB);
      topk_kernel<<<RB, 256, 0, stream>>>(S, fidx, fval, rb * RB);
    }
  }

  feat_deg_kernel<<<MT / 256, 256, 0, stream>>>(fidx, fval, frow);
  prep_kernel<<<MT, 64, 0, stream>>>(frow, pmask, Psi, U, V);
  gather_feat_kernel<<<MT, 64, 0, stream>>>(fidx, fval, U, Wf);
  gather_pix_kernel<<<MT, 64, 0, stream>>>(pmask, V, W2);
  rmat_part_kernel<<<RPB, 256, 0, stream>>>(U, Wf, V, W2, Pf, Pp);
  rmat_reduce_kernel<<<16, 256, 0, stream>>>(Pf, Pp, Rm);
  final_kernel<<<1, 256, 0, stream>>>(Rm, out);
}

// Round 7
// 533.308 us; speedup vs baseline: 2.7738x; 1.0770x over previous
//
#include <hip/hip_runtime.h>
#include <hip/hip_bf16.h>
#include <math.h>

// Problem constants (Segmenter_65721589563708)
constexpr int MT  = 8192;   // bs*n
constexpr int DF  = 768;    // feature dim
constexpr int KD  = 64;     // kdim
constexpr int HWP = 1024;   // 32*32 pixels
constexpr int KF  = 32;     // feature kNN
constexpr int KP  = 10;     // pixel kNN
constexpr int RB  = 1024;   // GEMM row-block (fallback path)
constexpr int RPB = 256;    // rmat partial blocks
#define SQT 3.16227766016837933f   // sqrt(T=10)
#define PIXW 0.05f

typedef __bf16 bf16x8 __attribute__((ext_vector_type(8)));
typedef float  f32x4  __attribute__((ext_vector_type(4)));
typedef _Float16 f16;
typedef _Float16 f16x8 __attribute__((ext_vector_type(8)));

// ---------------- 1. normalize rows of X -> bf16 ----------------
__global__ __launch_bounds__(256) void norm_kernel(const float* __restrict__ X,
                                                   __bf16* __restrict__ Xb) {
  __shared__ float red[256];
  const int row = blockIdx.x, tid = threadIdx.x;
  const float* xr = X + (size_t)row * DF;
  float s = 0.f;
  for (int c = tid; c < DF; c += 256) { float v = xr[c]; s += v * v; }
  red[tid] = s; __syncthreads();
  for (int o = 128; o > 0; o >>= 1) { if (tid < o) red[tid] += red[tid + o]; __syncthreads(); }
  const float rn = rsqrtf(red[0]);
  __bf16* hr = Xb + (size_t)row * DF;
  for (int c = tid; c < DF; c += 256) hr[c] = (__bf16)(xr[c] * rn);
}

// ---------------- 2. S = Xb . Xb^T  (bf16 MFMA -> fp16 S, XOR-swizzled LDS) ----------
template <bool SYM>
__global__ __launch_bounds__(256) void gemm_kernel(const __bf16* __restrict__ Xb,
                                                   f16* __restrict__ S, int rowBase) {
  __shared__ __bf16 As[128 * 64];
  __shared__ __bf16 Bs[128 * 64];
  const int tid = threadIdx.x;
  const int lane = tid & 63;
  const int wv = tid >> 6;
  const int wm = (wv & 1) * 64, wn = (wv >> 1) * 64;
  const int l15 = lane & 15, lq = lane >> 4;
  const int lr8 = lane >> 3, lc8 = lane & 7;   // staging: row-in-group, 16B chunk
  const int rsw = l15 & 7;                     // fragment-row swizzle key

  int m0, n0;
  if (SYM) {
    int L = blockIdx.x, ti = 0;
    while (L >= 64 - ti) { L -= 64 - ti; ++ti; }
    m0 = ti * 128;
    n0 = (ti + L) * 128;
  } else {
    m0 = rowBase + blockIdx.y * 128;
    n0 = blockIdx.x * 128;
  }

  f32x4 acc[4][4];
  #pragma unroll
  for (int i = 0; i < 4; ++i)
    #pragma unroll
    for (int j = 0; j < 4; ++j)
      #pragma unroll
      for (int r = 0; r < 4; ++r) acc[i][j][r] = 0.f;

  for (int kt = 0; kt < 12; ++kt) {
    const int col0 = kt * 64;
    const __bf16* Ag = Xb + (size_t)m0 * DF + col0;
    const __bf16* Bg = Xb + (size_t)n0 * DF + col0;
    #pragma unroll
    for (int i = 0; i < 4; ++i) {
      const int r0 = (wv * 4 + i) * 8;         // 8 rows per issue, wave-uniform base
      const int csw = (lc8 ^ lr8) * 8;
      __builtin_amdgcn_global_load_lds(
          (const __attribute__((address_space(1))) void*)(Ag + (size_t)(r0 + lr8) * DF + csw),
          (__attribute__((address_space(3))) void*)(&As[r0 * 64]), 16, 0, 0);
      __builtin_amdgcn_global_load_lds(
          (const __attribute__((address_space(1))) void*)(Bg + (size_t)(r0 + lr8) * DF + csw),
          (__attribute__((address_space(3))) void*)(&Bs[r0 * 64]), 16, 0, 0);
    }
    __syncthreads();
    #pragma unroll
    for (int kk = 0; kk < 64; kk += 32) {
      bf16x8 af[4], bg[4];
      #pragma unroll
      for (int i = 0; i < 4; ++i)
        af[i] = *(const bf16x8*)(&As[(wm + i * 16 + l15) * 64 + ((((kk >> 3) + lq) ^ rsw) * 8)]);
      #pragma unroll
      for (int j = 0; j < 4; ++j)
        bg[j] = *(const bf16x8*)(&Bs[(wn + j * 16 + l15) * 64 + ((((kk >> 3) + lq) ^ rsw) * 8)]);
      #pragma unroll
      for (int i = 0; i < 4; ++i)
        #pragma unroll
        for (int j = 0; j < 4; ++j)
          acc[i][j] = __builtin_amdgcn_mfma_f32_16x16x32_bf16(af[i], bg[j], acc[i][j], 0, 0, 0);
    }
    __syncthreads();
  }
  #pragma unroll
  for (int i = 0; i < 4; ++i)
    #pragma unroll
    for (int j = 0; j < 4; ++j)
      #pragma unroll
      for (int r = 0; r < 4; ++r) {
        const int lrow = m0 + wm + i * 16 + lq * 4 + r;
        const int col  = n0 + wn + j * 16 + l15;
        const f16 v = (f16)acc[i][j][r];
        if (SYM) {
          S[(size_t)lrow * MT + col] = v;
          S[(size_t)col * MT + lrow] = v;   // mirror; diag tiles: bitwise-identical benign race
        } else {
          S[(size_t)(lrow - rowBase) * MT + col] = v;
        }
      }
}

// ---------------- 3. top-32 per row: vectorized f16x8 loads (no d16 scalar loads!) --------
constexpr int NB   = 1024;   // histogram bins over [0,1]
constexpr int CAND = 2048;   // candidate cap (expected ~33 with random data)

__global__ __launch_bounds__(256) void topk_kernel(const f16* __restrict__ Sblk,
                                                   int* __restrict__ fidx,
                                                   float* __restrict__ fval, int rowBase) {
  __shared__ int   hist[NB];
  __shared__ int   chunk[256];
  __shared__ float cval[CAND];
  __shared__ int   cidx[CAND];
  __shared__ int   cnt, tbin;
  const int tid = threadIdx.x;
  const int rl = blockIdx.x;
  const int grow = rowBase + rl;
  const f16x8* srow8 = (const f16x8*)(Sblk + (size_t)rl * MT);
  float vals[32];
  #pragma unroll
  for (int i = tid; i < NB; i += 256) hist[i] = 0;
  if (tid == 0) cnt = 0;
  __syncthreads();
  // pass 1: 4 stripes x one dwordx4 load (8 halves), unpack to registers, histogram
  #pragma unroll
  for (int i = 0; i < 4; ++i) {
    const f16x8 pk = srow8[i * 256 + tid];
    const int c0 = i * 2048 + tid * 8;
    #pragma unroll
    for (int j = 0; j < 8; ++j) {
      float v = (float)pk[j];
      if (c0 + j == grow) v = -1.f;
      vals[i * 8 + j] = v;
      if (v > 0.f) {
        int b = (int)fminf(v * (float)NB, (float)(NB - 1));
        atomicAdd(&hist[b], 1);
      }
    }
  }
  __syncthreads();
  { int s = 0;
    #pragma unroll
    for (int i = 0; i < 4; ++i) s += hist[tid * 4 + i];
    chunk[tid] = s; }
  __syncthreads();
  if (tid == 0) {
    int acc = 0, ch = 255;
    for (; ch > 0; --ch) {
      if (acc + chunk[ch] >= KF) break;
      acc += chunk[ch];
    }
    int b = ch * 4 + 3;
    for (; b > ch * 4; --b) {
      if (acc + hist[b] >= KF) break;
      acc += hist[b];
    }
    tbin = b;
  }
  __syncthreads();
  const float thr = (float)tbin * (1.f / (float)NB);
  // pass 2: collect candidates from registers
  #pragma unroll
  for (int i = 0; i < 4; ++i) {
    const int c0 = i * 2048 + tid * 8;
    #pragma unroll
    for (int j = 0; j < 8; ++j) {
      float v = vals[i * 8 + j];
      if (v > 0.f && v >= thr) {
        int pos = atomicAdd(&cnt, 1);
        if (pos < CAND) { cval[pos] = v; cidx[pos] = c0 + j; }
      }
    }
  }
  __syncthreads();
  const int n = min(cnt, CAND);
  // wave 0: iterative argmax over ~33 candidates
  if (tid < 64) {
    for (int it = 0; it < KF; ++it) {
      float bm = -1.f; int bp = -1;
      for (int e = tid; e < n; e += 64)
        if (cval[e] > bm) { bm = cval[e]; bp = e; }
      #pragma unroll
      for (int o = 32; o > 0; o >>= 1) {
        float ov = __shfl_down(bm, o);
        int   op = __shfl_down(bp, o);
        if (ov > bm) { bm = ov; bp = op; }
      }
      bm = __shfl(bm, 0); bp = __shfl(bp, 0);
      if (tid == 0) {
        if (bp >= 0) {
          fval[(size_t)grow * KF + it] = bm;
          fidx[(size_t)grow * KF + it] = cidx[bp];
          cval[bp] = -2.f;
        } else {
          fval[(size_t)grow * KF + it] = 0.f;
          fidx[(size_t)grow * KF + it] = grow;
        }
      }
    }
  }
}

// ---------------- 4. pixel kNN: one wave per pixel, register-resident distances ----------------
__global__ __launch_bounds__(256) void pix_topk_kernel(const float* __restrict__ im,
                                                       unsigned* __restrict__ pmask) {
  __shared__ float fr[HWP], fg[HWP], fb[HWP];
  const int tid = threadIdx.x;
  const int lane = tid & 63, wv = tid >> 6;
  const int b = blockIdx.x >> 8;
  const int p = ((blockIdx.x & 255) << 2) + wv;
  const float* imb = im + (size_t)b * 3 * HWP;
  for (int q = tid; q < HWP; q += 256) {
    fr[q] = imb[q]; fg[q] = imb[HWP + q]; fb[q] = imb[2 * HWP + q];
  }
  __syncthreads();
  const float pr = fr[p], pg = fg[p], pb = fb[p];
  const float px = (float)(p & 31) * (1.f / 31.f), py = (float)(p >> 5) * (1.f / 31.f);
  float d0[16], d1[16];
  #pragma unroll
  for (int i = 0; i < 16; ++i) {
    const int q = lane + (i << 6);
    float dr = (fr[q] - pr) * 0.5f, dg = (fg[q] - pg) * 0.5f, db = (fb[q] - pb) * 0.5f;
    float drgb = dr * dr + dg * dg + db * db;
    float dx = (float)(q & 31) * (1.f / 31.f) - px;
    float dy = (float)(q >> 5) * (1.f / 31.f) - py;
    float cd = dx * dx + dy * dy;
    d0[i] = (q == p) ? 1e30f : drgb + 4.00f * cd;   // dw = 2.0
    d1[i] = (q == p) ? 1e30f : drgb + 0.01f * cd;   // dw = 0.1
  }
  const int mrow = (b << 10) + p;
  auto doPass = [&](float (&dd)[16]) {
    for (int it = 0; it < KP; ++it) {
      float bm = 1e30f; int bq = 0;
      #pragma unroll
      for (int i = 0; i < 16; ++i) {
        const int q = lane + (i << 6);
        if (dd[i] < bm) { bm = dd[i]; bq = q; }
      }
      #pragma unroll
      for (int o = 32; o > 0; o >>= 1) {
        float ov = __shfl_down(bm, o);
        int   oq = __shfl_down(bq, o);
        if (ov < bm) { bm = ov; bq = oq; }
      }
      bq = __shfl(bq, 0);
      if (lane == 0) {
        atomicOr(&pmask[(size_t)mrow * 32 + (bq >> 5)], 1u << (bq & 31));
        atomicOr(&pmask[((size_t)((b << 10) + bq)) * 32 + (p >> 5)], 1u << (p & 31));
      }
      #pragma unroll
      for (int i = 0; i < 16; ++i)
        if (lane + (i << 6) == bq) dd[i] = 1e30f;
    }
  };
  doPass(d0);
  doPass(d1);
}

// ---------------- 5. feature degrees (row sums of (res+res^T)/2) ----------------
__global__ void feat_deg_kernel(const int* __restrict__ fidx, const float* __restrict__ fval,
                                float* __restrict__ frow) {
  int m = blockIdx.x * blockDim.x + threadIdx.x;
  if (m >= MT) return;
  float s = 0.f;
  for (int k = 0; k < KF; ++k) {
    float v = fval[m * KF + k];
    s += v;
    atomicAdd(&frow[fidx[m * KF + k]], 0.5f * v);
  }
  atomicAdd(&frow[m], 0.5f * s);
}

// ---------------- 6. prep: U = dfeat*sqrt(T)*Psi, V = d2r*sqrt(T)*Psi ----------------
__global__ __launch_bounds__(64) void prep_kernel(const float* __restrict__ frow,
                                                  const unsigned* __restrict__ pmask,
                                                  const float* __restrict__ Psi,
                                                  float* __restrict__ U,
                                                  float* __restrict__ V) {
  const int m = blockIdx.x, t = threadIdx.x;
  int pd = (t < 32) ? __popc(pmask[(size_t)m * 32 + t]) : 0;
  #pragma unroll
  for (int o = 16; o > 0; o >>= 1) pd += __shfl_down(pd, o);
  pd = __shfl(pd, 0);
  const float fr = frow[m];
  const float df = (fr > 0.f) ? rsqrtf(fr) : 0.f;
  const float dp = (pd > 0) ? rsqrtf((float)pd) : 0.f;
  const float p = Psi[(size_t)m * KD + t] * SQT;
  U[(size_t)m * KD + t] = df * p;
  V[(size_t)m * KD + t] = dp * p;
}

// ---------------- 7. Wf[j] = sum_k 0.5*v_jk * U[c_jk]   (pure gather, no atomics) ---------
__global__ __launch_bounds__(64) void gather_feat_kernel(const int* __restrict__ fidx,
                                                         const float* __restrict__ fval,
                                                         const float* __restrict__ U,
                                                         float* __restrict__ Wf) {
  const int j = blockIdx.x, t = threadIdx.x;
  float acc = 0.f;
  for (int k = 0; k < KF; ++k) {
    float v = fval[j * KF + k];
    int   c = fidx[j * KF + k];
    acc += 0.5f * v * U[(size_t)c * KD + t];
  }
  Wf[(size_t)j * KD + t] = acc;
}

// ---------------- 8. W2[m] = sum_{q in adj(m)} V[q]   (pure gather) ----------------
__global__ __launch_bounds__(64) void gather_pix_kernel(const unsigned* __restrict__ pmask,
                                                        const float* __restrict__ V,
                                                        float* __restrict__ W2) {
  __shared__ int list[HWP];
  __shared__ int cnt;
  const int m = blockIdx.x;
  const int t = threadIdx.x;
  const int b = m >> 10;
  if (t == 0) cnt = 0;
  __syncthreads();
  if (t < 32) {
    unsigned bits = pmask[(size_t)m * 32 + t];
    while (bits) {
      int bit = __ffs(bits) - 1;
      bits &= bits - 1;
      int pos = atomicAdd(&cnt, 1);
      list[pos] = t * 32 + bit;
    }
  }
  __syncthreads();
  const int n = cnt;
  float acc = 0.f;
  for (int e = 0; e < n; ++e)
    acc += V[(size_t)(b * HWP + list[e]) * KD + t];
  W2[(size_t)m * KD + t] = acc;
}

// ---------------- 9a. partial products: Pf[b] = U[rows]^T Wf[rows], Pp likewise -----------
__global__ __launch_bounds__(256) void rmat_part_kernel(const float* __restrict__ U,
                                                        const float* __restrict__ Wf,
                                                        const float* __restrict__ V,
                                                        const float* __restrict__ W2,
                                                        float* __restrict__ Pf,
                                                        float* __restrict__ Pp) {
  __shared__ float sU[8][KD], sWf[8][KD], sV[8][KD], sW2[8][KD];
  const int tid = threadIdx.x;
  const int c = tid & 63, g = tid >> 6;
  float accf[16], accp[16];
  #pragma unroll
  for (int i = 0; i < 16; ++i) { accf[i] = 0.f; accp[i] = 0.f; }
  const int rowBeg = blockIdx.x * (MT / RPB);
  for (int r0 = rowBeg; r0 < rowBeg + MT / RPB; r0 += 8) {
    #pragma unroll
    for (int e = tid; e < 8 * KD; e += 256) {
      const int r = e >> 6, cc = e & 63;
      const size_t gi = (size_t)(r0 + r) * KD + cc;
      sU[r][cc]  = U[gi];
      sWf[r][cc] = Wf[gi];
      sV[r][cc]  = V[gi];
      sW2[r][cc] = W2[gi];
    }
    __syncthreads();
    #pragma unroll
    for (int r = 0; r < 8; ++r) {
      const float wf = sWf[r][c], w2 = sW2[r][c];
      const f32x4* u4 = (const f32x4*)&sU[r][g * 16];
      const f32x4* v4 = (const f32x4*)&sV[r][g * 16];
      #pragma unroll
      for (int q = 0; q < 4; ++q) {
        const f32x4 uu = u4[q], vv = v4[q];
        #pragma unroll
        for (int k = 0; k < 4; ++k) {
          accf[q * 4 + k] += uu[k] * wf;
          accp[q * 4 + k] += vv[k] * w2;
        }
      }
    }
    __syncthreads();
  }
  float* pf = Pf + (size_t)blockIdx.x * KD * KD;
  float* pp = Pp + (size_t)blockIdx.x * KD * KD;
  #pragma unroll
  for (int i = 0; i < 16; ++i) {
    const int a = g * 16 + i;
    pf[a * KD + c] = accf[i];
    pp[a * KD + c] = accp[i];
  }
}

// ---------------- 9b. Rm = sum_b (Pf[b] + Pf[b]^T + PIXW*Pp[b]) ----------------
__global__ __launch_bounds__(256) void rmat_reduce_kernel(const float* __restrict__ Pf,
                                                          const float* __restrict__ Pp,
                                                          float* __restrict__ Rm) {
  const int e = blockIdx.x * 256 + threadIdx.x;   // 16 blocks
  const int a = e >> 6, c = e & 63;
  const int eT = c * KD + a;
  float f = 0.f, ft = 0.f, p = 0.f;
  #pragma unroll 8
  for (int b = 0; b < RPB; ++b) {
    f  += Pf[(size_t)b * KD * KD + e];
    ft += Pf[(size_t)b * KD * KD + eT];
    p  += Pp[(size_t)b * KD * KD + e];
  }
  Rm[e] = f + ft + PIXW * p;
}

// ---------------- 10. loss = -tr(R)/kd ; reg = sum(triu(R^2,1))/kd ----------------
__global__ __launch_bounds__(256) void final_kernel(const float* __restrict__ Rm,
                                                    float* __restrict__ out) {
  __shared__ float redt[256], redr[256];
  const int tid = threadIdx.x;
  float tr = 0.f, rg = 0.f;
  for (int e = tid; e < KD * KD; e += 256) {
    int a = e >> 6, c = e & 63;
    float v = Rm[e];
    if (a == c) tr += v;
    else if (c > a) rg += v * v;
  }
  redt[tid] = tr; redr[tid] = rg;
  __syncthreads();
  for (int o = 128; o > 0; o >>= 1) {
    if (tid < o) { redt[tid] += redt[tid + o]; redr[tid] += redr[tid + o]; }
    __syncthreads();
  }
  if (tid == 0) {
    out[0] = -redt[0] / (float)KD;
    out[1] = redr[0] / (float)KD;
  }
}

extern "C" void kernel_launch(void* const* d_in, const int* in_sizes, int n_in,
                              void* d_out, int out_size, void* d_ws, size_t ws_size,
                              hipStream_t stream) {
  const float* hl  = (const float*)d_in[0];   // [8,1024,768]
  const float* Psi = (const float*)d_in[1];   // [8,1024,64]
  const float* im  = (const float*)d_in[2];   // [8,3,32,32]
  float* out = (float*)d_out;

  const size_t smallBytes = (size_t)MT * DF * 2 + (size_t)MT * KF * 8 + (size_t)MT * 4 +
                            (size_t)MT * 32 * 4 + (size_t)MT * KD * 4 * 4 +
                            (size_t)RPB * KD * KD * 4 * 2 + (size_t)KD * KD * 4 + 32 * 4096;
  const bool fullS = ws_size >= (size_t)MT * MT * 2 + smallBytes;

  char* ws = (char*)d_ws;
  size_t off = 0;
  auto alloc = [&](size_t bytes) -> void* {
    void* p = ws + off;
    off = (off + bytes + 255) & ~(size_t)255;
    return p;
  };
  f16*      S     = (f16*)alloc(fullS ? (size_t)MT * MT * 2 : (size_t)RB * MT * 2);
  __bf16*   Xb    = (__bf16*)alloc((size_t)MT * DF * 2);
  int*      fidx  = (int*)alloc((size_t)MT * KF * 4);
  float*    fval  = (float*)alloc((size_t)MT * KF * 4);
  float*    frow  = (float*)alloc((size_t)MT * 4);
  unsigned* pmask = (unsigned*)alloc((size_t)MT * 32 * 4);
  float*    U     = (float*)alloc((size_t)MT * KD * 4);
  float*    V     = (float*)alloc((size_t)MT * KD * 4);
  float*    Wf    = (float*)alloc((size_t)MT * KD * 4);
  float*    W2    = (float*)alloc((size_t)MT * KD * 4);
  float*    Pf    = (float*)alloc((size_t)RPB * KD * KD * 4);
  float*    Pp    = (float*)alloc((size_t)RPB * KD * KD * 4);
  float*    Rm    = (float*)alloc((size_t)KD * KD * 4);

  hipMemsetAsync(frow,  0, (size_t)MT * 4, stream);
  hipMemsetAsync(pmask, 0, (size_t)MT * 32 * 4, stream);

  norm_kernel<<<MT, 256, 0, stream>>>(hl, Xb);
  pix_topk_kernel<<<MT / 4, 256, 0, stream>>>(im, pmask);

  if (fullS) {
    gemm_kernel<true><<<2080, 256, 0, stream>>>(Xb, S, 0);
    topk_kernel<<<MT, 256, 0, stream>>>(S, fidx, fval, 0);
  } else {
    for (int rb = 0; rb < MT / RB; ++rb) {
      gemm_kernel<false><<<dim3(MT / 128, RB / 128), 256, 0, stream>>>(Xb, S, rb * RB);
      topk_kernel<<<RB, 256, 0, stream>>>(S, fidx, fval, rb * RB);
    }
  }

  feat_deg_kernel<<<MT / 256, 256, 0, stream>>>(fidx, fval, frow);
  prep_kernel<<<MT, 64, 0, stream>>>(frow, pmask, Psi, U, V);
  gather_feat_kernel<<<MT, 64, 0, stream>>>(fidx, fval, U, Wf);
  gather_pix_kernel<<<MT, 64, 0, stream>>>(pmask, V, W2);
  rmat_part_kernel<<<RPB, 256, 0, stream>>>(U, Wf, V, W2, Pf, Pp);
  rmat_reduce_kernel<<<16, 256, 0, stream>>>(Pf, Pp, Rm);
  final_kernel<<<1, 256, 0, stream>>>(Rm, out);
}

// Round 8
// 468.031 us; speedup vs baseline: 3.1606x; 1.1395x over previous
//
#include <hip/hip_runtime.h>
#include <hip/hip_bf16.h>
#include <math.h>

// Problem constants (Segmenter_65721589563708)
constexpr int MT  = 8192;   // bs*n
constexpr int DF  = 768;    // feature dim
constexpr int KD  = 64;     // kdim
constexpr int HWP = 1024;   // 32*32 pixels
constexpr int KF  = 32;     // feature kNN
constexpr int KP  = 10;     // pixel kNN
constexpr int RB  = 1024;   // GEMM row-block (fallback path)
constexpr int RPB = 256;    // rmat partial blocks
#define SQT 3.16227766016837933f   // sqrt(T=10)
#define PIXW 0.05f

typedef __bf16 bf16x8 __attribute__((ext_vector_type(8)));
typedef float  f32x4  __attribute__((ext_vector_type(4)));
typedef _Float16 f16;
typedef _Float16 f16x8 __attribute__((ext_vector_type(8)));

// ---------------- 1. normalize rows of X -> bf16 ----------------
__global__ __launch_bounds__(256) void norm_kernel(const float* __restrict__ X,
                                                   __bf16* __restrict__ Xb) {
  __shared__ float red[256];
  const int row = blockIdx.x, tid = threadIdx.x;
  const float* xr = X + (size_t)row * DF;
  float s = 0.f;
  for (int c = tid; c < DF; c += 256) { float v = xr[c]; s += v * v; }
  red[tid] = s; __syncthreads();
  for (int o = 128; o > 0; o >>= 1) { if (tid < o) red[tid] += red[tid + o]; __syncthreads(); }
  const float rn = rsqrtf(red[0]);
  __bf16* hr = Xb + (size_t)row * DF;
  for (int c = tid; c < DF; c += 256) hr[c] = (__bf16)(xr[c] * rn);
}

// ---------------- 2. S = Xb . Xb^T  (bf16 MFMA -> fp16 S, XOR-swizzled LDS) ----------
template <bool SYM>
__global__ __launch_bounds__(256) void gemm_kernel(const __bf16* __restrict__ Xb,
                                                   f16* __restrict__ S, int rowBase) {
  __shared__ __bf16 As[128 * 64];
  __shared__ __bf16 Bs[128 * 64];
  const int tid = threadIdx.x;
  const int lane = tid & 63;
  const int wv = tid >> 6;
  const int wm = (wv & 1) * 64, wn = (wv >> 1) * 64;
  const int l15 = lane & 15, lq = lane >> 4;
  const int lr8 = lane >> 3, lc8 = lane & 7;   // staging: row-in-group, 16B chunk
  const int rsw = l15 & 7;                     // fragment-row swizzle key

  int m0, n0;
  if (SYM) {
    int L = blockIdx.x, ti = 0;
    while (L >= 64 - ti) { L -= 64 - ti; ++ti; }
    m0 = ti * 128;
    n0 = (ti + L) * 128;
  } else {
    m0 = rowBase + blockIdx.y * 128;
    n0 = blockIdx.x * 128;
  }

  f32x4 acc[4][4];
  #pragma unroll
  for (int i = 0; i < 4; ++i)
    #pragma unroll
    for (int j = 0; j < 4; ++j)
      #pragma unroll
      for (int r = 0; r < 4; ++r) acc[i][j][r] = 0.f;

  for (int kt = 0; kt < 12; ++kt) {
    const int col0 = kt * 64;
    const __bf16* Ag = Xb + (size_t)m0 * DF + col0;
    const __bf16* Bg = Xb + (size_t)n0 * DF + col0;
    #pragma unroll
    for (int i = 0; i < 4; ++i) {
      const int r0 = (wv * 4 + i) * 8;         // 8 rows per issue, wave-uniform base
      const int csw = (lc8 ^ lr8) * 8;
      __builtin_amdgcn_global_load_lds(
          (const __attribute__((address_space(1))) void*)(Ag + (size_t)(r0 + lr8) * DF + csw),
          (__attribute__((address_space(3))) void*)(&As[r0 * 64]), 16, 0, 0);
      __builtin_amdgcn_global_load_lds(
          (const __attribute__((address_space(1))) void*)(Bg + (size_t)(r0 + lr8) * DF + csw),
          (__attribute__((address_space(3))) void*)(&Bs[r0 * 64]), 16, 0, 0);
    }
    __syncthreads();
    #pragma unroll
    for (int kk = 0; kk < 64; kk += 32) {
      bf16x8 af[4], bg[4];
      #pragma unroll
      for (int i = 0; i < 4; ++i)
        af[i] = *(const bf16x8*)(&As[(wm + i * 16 + l15) * 64 + ((((kk >> 3) + lq) ^ rsw) * 8)]);
      #pragma unroll
      for (int j = 0; j < 4; ++j)
        bg[j] = *(const bf16x8*)(&Bs[(wn + j * 16 + l15) * 64 + ((((kk >> 3) + lq) ^ rsw) * 8)]);
      #pragma unroll
      for (int i = 0; i < 4; ++i)
        #pragma unroll
        for (int j = 0; j < 4; ++j)
          acc[i][j] = __builtin_amdgcn_mfma_f32_16x16x32_bf16(af[i], bg[j], acc[i][j], 0, 0, 0);
    }
    __syncthreads();
  }
  #pragma unroll
  for (int i = 0; i < 4; ++i)
    #pragma unroll
    for (int j = 0; j < 4; ++j)
      #pragma unroll
      for (int r = 0; r < 4; ++r) {
        const int lrow = m0 + wm + i * 16 + lq * 4 + r;
        const int col  = n0 + wn + j * 16 + l15;
        const f16 v = (f16)acc[i][j][r];
        if (SYM) {
          S[(size_t)lrow * MT + col] = v;
          S[(size_t)col * MT + lrow] = v;   // mirror; diag tiles: bitwise-identical benign race
        } else {
          S[(size_t)(lrow - rowBase) * MT + col] = v;
        }
      }
}

// ---------------- 3. top-32: fixed statistical threshold + parallel rank select ----------
// sims ~ N(0, 1/768): thr=0.07 keeps ~215 +- 14 candidates (13-sigma above KF=32,
// 37-sigma below CAND). Fallback (never taken on this data) = register argmax rounds.
constexpr int   CAND    = 1024;
#define THR_SEL 0.07f

__global__ __launch_bounds__(256) void topk_kernel(const f16* __restrict__ Sblk,
                                                   int* __restrict__ fidx,
                                                   float* __restrict__ fval, int rowBase) {
  __shared__ float cval[CAND];
  __shared__ int   cidx[CAND];
  __shared__ int   cnt;
  __shared__ float rv[4];
  __shared__ int   ri[4];
  __shared__ int   win;
  const int tid = threadIdx.x;
  const int rl = blockIdx.x;
  const int grow = rowBase + rl;
  const f16x8* srow8 = (const f16x8*)(Sblk + (size_t)rl * MT);
  float vals[32];
  if (tid == 0) cnt = 0;
  __syncthreads();
  // single pass: vector loads, collect candidates >= THR_SEL
  #pragma unroll
  for (int i = 0; i < 4; ++i) {
    const f16x8 pk = srow8[i * 256 + tid];
    const int c0 = i * 2048 + tid * 8;
    #pragma unroll
    for (int j = 0; j < 8; ++j) {
      float v = (float)pk[j];
      const int c = c0 + j;
      if (c == grow) v = -1.f;
      vals[i * 8 + j] = v;
      if (v >= THR_SEL) {
        int pos = atomicAdd(&cnt, 1);
        if (pos < CAND) { cval[pos] = v; cidx[pos] = c; }
      }
    }
  }
  __syncthreads();
  const int n = cnt;
  if (n >= KF && n <= CAND) {
    // parallel rank: rank(e) = #{j : v_j > v_e or (v_j==v_e and idx_j < idx_e)}
    for (int e = tid; e < n; e += 256) {
      const float v = cval[e];
      const int   ci = cidx[e];
      int rank = 0;
      for (int j = 0; j < n; ++j) {
        const float u = cval[j];
        rank += (u > v) || (u == v && cidx[j] < ci);
      }
      if (rank < KF) {
        fval[(size_t)grow * KF + rank] = v;
        fidx[(size_t)grow * KF + rank] = ci;
      }
    }
  } else {
    // fallback: 32 rounds of block-wide argmax over register-resident row (never taken)
    for (int it = 0; it < KF; ++it) {
      float bm = -3.f; int bc = -1;
      #pragma unroll
      for (int i = 0; i < 32; ++i)
        if (vals[i] > bm) { bm = vals[i]; bc = (i >> 3) * 2048 + tid * 8 + (i & 7); }
      #pragma unroll
      for (int o = 32; o > 0; o >>= 1) {
        float ov = __shfl_down(bm, o);
        int   oc = __shfl_down(bc, o);
        if (ov > bm) { bm = ov; bc = oc; }
      }
      if ((tid & 63) == 0) { rv[tid >> 6] = bm; ri[tid >> 6] = bc; }
      __syncthreads();
      if (tid == 0) {
        float m = rv[0]; int mc = ri[0];
        #pragma unroll
        for (int q = 1; q < 4; ++q) if (rv[q] > m) { m = rv[q]; mc = ri[q]; }
        if (m <= 0.f) { fval[(size_t)grow * KF + it] = 0.f; fidx[(size_t)grow * KF + it] = grow; win = -1; }
        else { fval[(size_t)grow * KF + it] = m; fidx[(size_t)grow * KF + it] = mc; win = mc; }
      }
      __syncthreads();
      const int w = win;
      if (w >= 0 && (w >> 3 == (tid << 0) + 0 || true)) {
        #pragma unroll
        for (int i = 0; i < 32; ++i)
          if ((i >> 3) * 2048 + tid * 8 + (i & 7) == w) vals[i] = -2.f;
      }
      __syncthreads();
    }
  }
}

// ---------------- 4. pixel kNN: one wave per pixel, register-resident distances ----------------
__global__ __launch_bounds__(256) void pix_topk_kernel(const float* __restrict__ im,
                                                       unsigned* __restrict__ pmask) {
  __shared__ float fr[HWP], fg[HWP], fb[HWP];
  const int tid = threadIdx.x;
  const int lane = tid & 63, wv = tid >> 6;
  const int b = blockIdx.x >> 8;
  const int p = ((blockIdx.x & 255) << 2) + wv;
  const float* imb = im + (size_t)b * 3 * HWP;
  for (int q = tid; q < HWP; q += 256) {
    fr[q] = imb[q]; fg[q] = imb[HWP + q]; fb[q] = imb[2 * HWP + q];
  }
  __syncthreads();
  const float pr = fr[p], pg = fg[p], pb = fb[p];
  const float px = (float)(p & 31) * (1.f / 31.f), py = (float)(p >> 5) * (1.f / 31.f);
  float d0[16], d1[16];
  #pragma unroll
  for (int i = 0; i < 16; ++i) {
    const int q = lane + (i << 6);
    float dr = (fr[q] - pr) * 0.5f, dg = (fg[q] - pg) * 0.5f, db = (fb[q] - pb) * 0.5f;
    float drgb = dr * dr + dg * dg + db * db;
    float dx = (float)(q & 31) * (1.f / 31.f) - px;
    float dy = (float)(q >> 5) * (1.f / 31.f) - py;
    float cd = dx * dx + dy * dy;
    d0[i] = (q == p) ? 1e30f : drgb + 4.00f * cd;   // dw = 2.0
    d1[i] = (q == p) ? 1e30f : drgb + 0.01f * cd;   // dw = 0.1
  }
  const int mrow = (b << 10) + p;
  auto doPass = [&](float (&dd)[16]) {
    for (int it = 0; it < KP; ++it) {
      float bm = 1e30f; int bq = 0;
      #pragma unroll
      for (int i = 0; i < 16; ++i) {
        const int q = lane + (i << 6);
        if (dd[i] < bm) { bm = dd[i]; bq = q; }
      }
      #pragma unroll
      for (int o = 32; o > 0; o >>= 1) {
        float ov = __shfl_down(bm, o);
        int   oq = __shfl_down(bq, o);
        if (ov < bm) { bm = ov; bq = oq; }
      }
      bq = __shfl(bq, 0);
      if (lane == 0) {
        atomicOr(&pmask[(size_t)mrow * 32 + (bq >> 5)], 1u << (bq & 31));
        atomicOr(&pmask[((size_t)((b << 10) + bq)) * 32 + (p >> 5)], 1u << (p & 31));
      }
      #pragma unroll
      for (int i = 0; i < 16; ++i)
        if (lane + (i << 6) == bq) dd[i] = 1e30f;
    }
  };
  doPass(d0);
  doPass(d1);
}

// ---------------- 5. feature degrees (row sums of (res+res^T)/2) ----------------
__global__ void feat_deg_kernel(const int* __restrict__ fidx, const float* __restrict__ fval,
                                float* __restrict__ frow) {
  int m = blockIdx.x * blockDim.x + threadIdx.x;
  if (m >= MT) return;
  float s = 0.f;
  for (int k = 0; k < KF; ++k) {
    float v = fval[m * KF + k];
    s += v;
    atomicAdd(&frow[fidx[m * KF + k]], 0.5f * v);
  }
  atomicAdd(&frow[m], 0.5f * s);
}

// ---------------- 6. prep: U = dfeat*sqrt(T)*Psi, V = d2r*sqrt(T)*Psi ----------------
__global__ __launch_bounds__(64) void prep_kernel(const float* __restrict__ frow,
                                                  const unsigned* __restrict__ pmask,
                                                  const float* __restrict__ Psi,
                                                  float* __restrict__ U,
                                                  float* __restrict__ V) {
  const int m = blockIdx.x, t = threadIdx.x;
  int pd = (t < 32) ? __popc(pmask[(size_t)m * 32 + t]) : 0;
  #pragma unroll
  for (int o = 16; o > 0; o >>= 1) pd += __shfl_down(pd, o);
  pd = __shfl(pd, 0);
  const float fr = frow[m];
  const float df = (fr > 0.f) ? rsqrtf(fr) : 0.f;
  const float dp = (pd > 0) ? rsqrtf((float)pd) : 0.f;
  const float p = Psi[(size_t)m * KD + t] * SQT;
  U[(size_t)m * KD + t] = df * p;
  V[(size_t)m * KD + t] = dp * p;
}

// ---------------- 7. Wf[j] = sum_k 0.5*v_jk * U[c_jk]   (pure gather, no atomics) ---------
__global__ __launch_bounds__(64) void gather_feat_kernel(const int* __restrict__ fidx,
                                                         const float* __restrict__ fval,
                                                         const float* __restrict__ U,
                                                         float* __restrict__ Wf) {
  const int j = blockIdx.x, t = threadIdx.x;
  float acc = 0.f;
  for (int k = 0; k < KF; ++k) {
    float v = fval[j * KF + k];
    int   c = fidx[j * KF + k];
    acc += 0.5f * v * U[(size_t)c * KD + t];
  }
  Wf[(size_t)j * KD + t] = acc;
}

// ---------------- 8. W2[m] = sum_{q in adj(m)} V[q]   (pure gather) ----------------
__global__ __launch_bounds__(64) void gather_pix_kernel(const unsigned* __restrict__ pmask,
                                                        const float* __restrict__ V,
                                                        float* __restrict__ W2) {
  __shared__ int list[HWP];
  __shared__ int cnt;
  const int m = blockIdx.x;
  const int t = threadIdx.x;
  const int b = m >> 10;
  if (t == 0) cnt = 0;
  __syncthreads();
  if (t < 32) {
    unsigned bits = pmask[(size_t)m * 32 + t];
    while (bits) {
      int bit = __ffs(bits) - 1;
      bits &= bits - 1;
      int pos = atomicAdd(&cnt, 1);
      list[pos] = t * 32 + bit;
    }
  }
  __syncthreads();
  const int n = cnt;
  float acc = 0.f;
  for (int e = 0; e < n; ++e)
    acc += V[(size_t)(b * HWP + list[e]) * KD + t];
  W2[(size_t)m * KD + t] = acc;
}

// ---------------- 9a. partial products: Pf[b] = U[rows]^T Wf[rows], Pp likewise -----------
__global__ __launch_bounds__(256) void rmat_part_kernel(const float* __restrict__ U,
                                                        const float* __restrict__ Wf,
                                                        const float* __restrict__ V,
                                                        const float* __restrict__ W2,
                                                        float* __restrict__ Pf,
                                                        float* __restrict__ Pp) {
  __shared__ float sU[8][KD], sWf[8][KD], sV[8][KD], sW2[8][KD];
  const int tid = threadIdx.x;
  const int c = tid & 63, g = tid >> 6;
  float accf[16], accp[16];
  #pragma unroll
  for (int i = 0; i < 16; ++i) { accf[i] = 0.f; accp[i] = 0.f; }
  const int rowBeg = blockIdx.x * (MT / RPB);
  for (int r0 = rowBeg; r0 < rowBeg + MT / RPB; r0 += 8) {
    #pragma unroll
    for (int e = tid; e < 8 * KD; e += 256) {
      const int r = e >> 6, cc = e & 63;
      const size_t gi = (size_t)(r0 + r) * KD + cc;
      sU[r][cc]  = U[gi];
      sWf[r][cc] = Wf[gi];
      sV[r][cc]  = V[gi];
      sW2[r][cc] = W2[gi];
    }
    __syncthreads();
    #pragma unroll
    for (int r = 0; r < 8; ++r) {
      const float wf = sWf[r][c], w2 = sW2[r][c];
      const f32x4* u4 = (const f32x4*)&sU[r][g * 16];
      const f32x4* v4 = (const f32x4*)&sV[r][g * 16];
      #pragma unroll
      for (int q = 0; q < 4; ++q) {
        const f32x4 uu = u4[q], vv = v4[q];
        #pragma unroll
        for (int k = 0; k < 4; ++k) {
          accf[q * 4 + k] += uu[k] * wf;
          accp[q * 4 + k] += vv[k] * w2;
        }
      }
    }
    __syncthreads();
  }
  float* pf = Pf + (size_t)blockIdx.x * KD * KD;
  float* pp = Pp + (size_t)blockIdx.x * KD * KD;
  #pragma unroll
  for (int i = 0; i < 16; ++i) {
    const int a = g * 16 + i;
    pf[a * KD + c] = accf[i];
    pp[a * KD + c] = accp[i];
  }
}

// ---------------- 9b. Rm = sum_b (Pf[b] + Pf[b]^T + PIXW*Pp[b]) ----------------
__global__ __launch_bounds__(256) void rmat_reduce_kernel(const float* __restrict__ Pf,
                                                          const float* __restrict__ Pp,
                                                          float* __restrict__ Rm) {
  const int e = blockIdx.x * 256 + threadIdx.x;   // 16 blocks
  const int a = e >> 6, c = e & 63;
  const int eT = c * KD + a;
  float f = 0.f, ft = 0.f, p = 0.f;
  #pragma unroll 8
  for (int b = 0; b < RPB; ++b) {
    f  += Pf[(size_t)b * KD * KD + e];
    ft += Pf[(size_t)b * KD * KD + eT];
    p  += Pp[(size_t)b * KD * KD + e];
  }
  Rm[e] = f + ft + PIXW * p;
}

// ---------------- 10. loss = -tr(R)/kd ; reg = sum(triu(R^2,1))/kd ----------------
__global__ __launch_bounds__(256) void final_kernel(const float* __restrict__ Rm,
                                                    float* __restrict__ out) {
  __shared__ float redt[256], redr[256];
  const int tid = threadIdx.x;
  float tr = 0.f, rg = 0.f;
  for (int e = tid; e < KD * KD; e += 256) {
    int a = e >> 6, c = e & 63;
    float v = Rm[e];
    if (a == c) tr += v;
    else if (c > a) rg += v * v;
  }
  redt[tid] = tr; redr[tid] = rg;
  __syncthreads();
  for (int o = 128; o > 0; o >>= 1) {
    if (tid < o) { redt[tid] += redt[tid + o]; redr[tid] += redr[tid + o]; }
    __syncthreads();
  }
  if (tid == 0) {
    out[0] = -redt[0] / (float)KD;
    out[1] = redr[0] / (float)KD;
  }
}

extern "C" void kernel_launch(void* const* d_in, const int* in_sizes, int n_in,
                              void* d_out, int out_size, void* d_ws, size_t ws_size,
                              hipStream_t stream) {
  const float* hl  = (const float*)d_in[0];   // [8,1024,768]
  const float* Psi = (const float*)d_in[1];   // [8,1024,64]
  const float* im  = (const float*)d_in[2];   // [8,3,32,32]
  float* out = (float*)d_out;

  const size_t smallBytes = (size_t)MT * DF * 2 + (size_t)MT * KF * 8 + (size_t)MT * 4 +
                            (size_t)MT * 32 * 4 + (size_t)MT * KD * 4 * 4 +
                            (size_t)RPB * KD * KD * 4 * 2 + (size_t)KD * KD * 4 + 32 * 4096;
  const bool fullS = ws_size >= (size_t)MT * MT * 2 + smallBytes;

  char* ws = (char*)d_ws;
  size_t off = 0;
  auto alloc = [&](size_t bytes) -> void* {
    void* p = ws + off;
    off = (off + bytes + 255) & ~(size_t)255;
    return p;
  };
  f16*      S     = (f16*)alloc(fullS ? (size_t)MT * MT * 2 : (size_t)RB * MT * 2);
  __bf16*   Xb    = (__bf16*)alloc((size_t)MT * DF * 2);
  int*      fidx  = (int*)alloc((size_t)MT * KF * 4);
  float*    fval  = (float*)alloc((size_t)MT * KF * 4);
  float*    frow  = (float*)alloc((size_t)MT * 4);
  unsigned* pmask = (unsigned*)alloc((size_t)MT * 32 * 4);
  float*    U     = (float*)alloc((size_t)MT * KD * 4);
  float*    V     = (float*)alloc((size_t)MT * KD * 4);
  float*    Wf    = (float*)alloc((size_t)MT * KD * 4);
  float*    W2    = (float*)alloc((size_t)MT * KD * 4);
  float*    Pf    = (float*)alloc((size_t)RPB * KD * KD * 4);
  float*    Pp    = (float*)alloc((size_t)RPB * KD * KD * 4);
  float*    Rm    = (float*)alloc((size_t)KD * KD * 4);

  hipMemsetAsync(frow,  0, (size_t)MT * 4, stream);
  hipMemsetAsync(pmask, 0, (size_t)MT * 32 * 4, stream);

  norm_kernel<<<MT, 256, 0, stream>>>(hl, Xb);
  pix_topk_kernel<<<MT / 4, 256, 0, stream>>>(im, pmask);

  if (fullS) {
    gemm_kernel<true><<<2080, 256, 0, stream>>>(Xb, S, 0);
    topk_kernel<<<MT, 256, 0, stream>>>(S, fidx, fval, 0);
  } else {
    for (int rb = 0; rb < MT / RB; ++rb) {
      gemm_kernel<false><<<dim3(MT / 128, RB / 128), 256, 0, stream>>>(Xb, S, rb * RB);
      topk_kernel<<<RB, 256, 0, stream>>>(S, fidx, fval, rb * RB);
    }
  }

  feat_deg_kernel<<<MT / 256, 256, 0, stream>>>(fidx, fval, frow);
  prep_kernel<<<MT, 64, 0, stream>>>(frow, pmask, Psi, U, V);
  gather_feat_kernel<<<MT, 64, 0, stream>>>(fidx, fval, U, Wf);
  gather_pix_kernel<<<MT, 64, 0, stream>>>(pmask, V, W2);
  rmat_part_kernel<<<RPB, 256, 0, stream>>>(U, Wf, V, W2, Pf, Pp);
  rmat_reduce_kernel<<<16, 256, 0, stream>>>(Pf, Pp, Rm);
  final_kernel<<<1, 256, 0, stream>>>(Rm, out);
}